// Round 1
// baseline (1248.424 us; speedup 1.0000x reference)
//
#include <hip/hip_runtime.h>
#include <hip/hip_bf16.h>

#define LN_EPS 1e-5f
#define B_SZ 2048
#define LCH 150
#define EE 16
#define HH 64
#define G4 256
#define KK 9600
#define KSPLIT 16

__device__ __forceinline__ float bf2f(unsigned short u) {
    return __uint_as_float(((unsigned int)u) << 16);
}
__device__ __forceinline__ unsigned short f2bf(float f) {
    unsigned int u = __float_as_uint(f);
    unsigned int r = (u + 0x7FFFu + ((u >> 16) & 1u)) >> 16;
    return (unsigned short)r;
}

// One block = one batch row. Thread g in [0,256) owns gate g.
// W_ih row (16 f) + W_hh row (64 f) live in registers; x_t and h broadcast from LDS.
__global__ __launch_bounds__(256)
void lstm_kernel(const int* __restrict__ idx, const float* __restrict__ eps,
                 const float* __restrict__ h0, const float* __restrict__ c0,
                 const float* __restrict__ mean_table, const float* __restrict__ var_table,
                 const float* __restrict__ W_ih, const float* __restrict__ W_hh,
                 const float* __restrict__ g_ih, const float* __restrict__ bln_ih,
                 const float* __restrict__ g_hh, const float* __restrict__ bln_hh,
                 const float* __restrict__ g_c, const float* __restrict__ bln_c,
                 unsigned short* __restrict__ hs_out)
{
    const int b = blockIdx.x;
    const int tid = threadIdx.x;
    const int lane = tid & 63;
    const int wid = tid >> 6;

    __shared__ float x_lds[LCH * EE];
    __shared__ float h_lds[HH];
    __shared__ float act_lds[G4];
    __shared__ float red_lds[16];

    float wih[EE];
    {
        const float4* p = (const float4*)(W_ih + tid * EE);
        #pragma unroll
        for (int q = 0; q < 4; ++q) {
            float4 v = p[q];
            wih[4*q+0] = v.x; wih[4*q+1] = v.y; wih[4*q+2] = v.z; wih[4*q+3] = v.w;
        }
    }
    float whh[HH];
    {
        const float4* p = (const float4*)(W_hh + tid * HH);
        #pragma unroll
        for (int q = 0; q < 16; ++q) {
            float4 v = p[q];
            whh[4*q+0] = v.x; whh[4*q+1] = v.y; whh[4*q+2] = v.z; whh[4*q+3] = v.w;
        }
    }
    const float gih = g_ih[tid], bih = bln_ih[tid];
    const float ghh = g_hh[tid], bhh = bln_hh[tid];

    // fused embedding gather + reparameterization into LDS
    if (tid < LCH) {
        const int id = idx[b * LCH + tid];
        const float4* mp = (const float4*)(mean_table + (size_t)id * EE);
        const float4* vp = (const float4*)(var_table + (size_t)id * EE);
        const float4* ep = (const float4*)(eps + ((size_t)b * LCH + tid) * EE);
        float4* xp = (float4*)(x_lds + tid * EE);
        #pragma unroll
        for (int q = 0; q < 4; ++q) {
            float4 m = mp[q], v = vp[q], e = ep[q], r;
            r.x = e.x * __expf(0.5f * v.x) + m.x;
            r.y = e.y * __expf(0.5f * v.y) + m.y;
            r.z = e.z * __expf(0.5f * v.z) + m.z;
            r.w = e.w * __expf(0.5f * v.w) + m.w;
            xp[q] = r;
        }
    }
    float c_reg = 0.f, gc = 0.f, bc = 0.f;
    if (tid < HH) {
        h_lds[tid] = h0[b * HH + tid];
        c_reg = c0[b * HH + tid];
        gc = g_c[tid]; bc = bln_c[tid];
    }
    __syncthreads();

    for (int t = 0; t < LCH; ++t) {
        float a_ih = 0.f;
        {
            const float4* xp = (const float4*)(x_lds + t * EE);
            #pragma unroll
            for (int q = 0; q < 4; ++q) {
                float4 x = xp[q];
                a_ih += x.x*wih[4*q+0] + x.y*wih[4*q+1] + x.z*wih[4*q+2] + x.w*wih[4*q+3];
            }
        }
        float a_hh = 0.f;
        {
            const float4* hp = (const float4*)h_lds;
            #pragma unroll
            for (int q = 0; q < 16; ++q) {
                float4 h = hp[q];
                a_hh += h.x*whh[4*q+0] + h.y*whh[4*q+1] + h.z*whh[4*q+2] + h.w*whh[4*q+3];
            }
        }
        // LN statistics over 256 gates (two independent LNs, 4 packed partials)
        float s0 = a_ih, s1 = a_ih * a_ih, s2 = a_hh, s3 = a_hh * a_hh;
        #pragma unroll
        for (int m = 1; m < 64; m <<= 1) {
            s0 += __shfl_xor(s0, m);
            s1 += __shfl_xor(s1, m);
            s2 += __shfl_xor(s2, m);
            s3 += __shfl_xor(s3, m);
        }
        if (lane == 0) ((float4*)red_lds)[wid] = make_float4(s0, s1, s2, s3);
        __syncthreads();
        float4 r0 = ((const float4*)red_lds)[0];
        float4 r1 = ((const float4*)red_lds)[1];
        float4 r2 = ((const float4*)red_lds)[2];
        float4 r3 = ((const float4*)red_lds)[3];
        const float inv = 1.f / 256.f;
        float m_ih = (r0.x + r1.x + r2.x + r3.x) * inv;
        float q_ih = (r0.y + r1.y + r2.y + r3.y) * inv;
        float m_hh = (r0.z + r1.z + r2.z + r3.z) * inv;
        float q_hh = (r0.w + r1.w + r2.w + r3.w) * inv;
        float gate = (a_ih - m_ih) * rsqrtf(q_ih - m_ih * m_ih + LN_EPS) * gih + bih
                   + (a_hh - m_hh) * rsqrtf(q_hh - m_hh * m_hh + LN_EPS) * ghh + bhh;
        // wave 0:i(sig) 1:f(sig) 2:g(tanh) 3:o(sig); wid is wave-uniform (no divergence)
        float act;
        if (wid == 2) {
            act = 2.f / (1.f + __expf(-2.f * gate)) - 1.f;   // tanh, saturates safely
        } else {
            act = 1.f / (1.f + __expf(-gate));               // sigmoid
        }
        act_lds[tid] = act;
        __syncthreads();
        if (tid < HH) {
            float iv = act_lds[tid], fv = act_lds[HH + tid];
            float gv = act_lds[2 * HH + tid], ov = act_lds[3 * HH + tid];
            c_reg = fv * c_reg + iv * gv;
            float t0 = c_reg, t1 = c_reg * c_reg;
            #pragma unroll
            for (int m = 1; m < 64; m <<= 1) {
                t0 += __shfl_xor(t0, m);
                t1 += __shfl_xor(t1, m);
            }
            const float inv64 = 1.f / 64.f;
            float mc = t0 * inv64;
            float vc = t1 * inv64 - mc * mc;
            float lnc = (c_reg - mc) * rsqrtf(vc + LN_EPS) * gc + bc;
            float th = 2.f / (1.f + __expf(-2.f * lnc)) - 1.f;
            float h_new = ov * th;
            h_lds[tid] = h_new;
            hs_out[(size_t)b * KK + t * HH + tid] = f2bf(h_new);
        }
        __syncthreads();
    }
}

// out_partial[seg][row][c] = sum over this segment's K-chunks of hs[row][k]*W_out[c][k]
// A staged transposed in LDS (conflict-free reads); W_out read at wave-uniform
// addresses (readfirstlane'd col group) -> scalarizable loads.
__global__ __launch_bounds__(256)
void gemm_kernel(const unsigned short* __restrict__ A, const float* __restrict__ W,
                 float* __restrict__ partial)
{
    const int mb = blockIdx.x;
    const int seg = blockIdx.y;
    const int tid = threadIdx.x;
    const int r = tid & 63;
    const int cgu = __builtin_amdgcn_readfirstlane(tid >> 6);  // 0..3, wave-uniform

    __shared__ float aT[64][64];   // aT[k][r]
    float acc[38];
    #pragma unroll
    for (int j = 0; j < 38; ++j) acc[j] = 0.f;

    const int row0 = mb * 64;
    // 150 chunks of 64 split over 16 segments: first 6 get 10, rest get 9
    const int c_start = seg * 9 + (seg < 6 ? seg : 6);
    const int nch = 9 + (seg < 6 ? 1 : 0);

    for (int ch = c_start; ch < c_start + nch; ++ch) {
        const int k0 = ch * 64;
        __syncthreads();
        #pragma unroll
        for (int n = 0; n < 4; ++n) {
            const int item = tid + n * 256;
            const int rr = item >> 4;
            const int q4 = item & 15;
            ushort4 hv = *(const ushort4*)(A + (size_t)(row0 + rr) * KK + k0 + q4 * 4);
            aT[q4 * 4 + 0][rr] = bf2f(hv.x);
            aT[q4 * 4 + 1][rr] = bf2f(hv.y);
            aT[q4 * 4 + 2][rr] = bf2f(hv.z);
            aT[q4 * 4 + 3][rr] = bf2f(hv.w);
        }
        __syncthreads();
        #pragma unroll 2
        for (int k4 = 0; k4 < 16; ++k4) {
            const float a0 = aT[k4 * 4 + 0][r];
            const float a1 = aT[k4 * 4 + 1][r];
            const float a2 = aT[k4 * 4 + 2][r];
            const float a3 = aT[k4 * 4 + 3][r];
            #pragma unroll
            for (int j = 0; j < 38; ++j) {
                int c = cgu * 38 + j; c = c < 150 ? c : 149;   // clamp (dup work, no OOB)
                const float4 bv = *(const float4*)(W + (size_t)c * KK + k0 + k4 * 4);
                acc[j] = fmaf(a0, bv.x, acc[j]);
                acc[j] = fmaf(a1, bv.y, acc[j]);
                acc[j] = fmaf(a2, bv.z, acc[j]);
                acc[j] = fmaf(a3, bv.w, acc[j]);
            }
        }
    }
    float* po = partial + ((size_t)seg * B_SZ + row0 + r) * 150;
    #pragma unroll
    for (int j = 0; j < 38; ++j) {
        const int c = cgu * 38 + j;
        if (c < 150) po[c] = acc[j];
    }
}

__global__ __launch_bounds__(256)
void reduce_kernel(const float* __restrict__ partial, const float* __restrict__ b_out,
                   float* __restrict__ out)
{
    const int i = blockIdx.x * 256 + threadIdx.x;
    if (i >= B_SZ * LCH) return;
    float s = 0.f;
    #pragma unroll
    for (int g = 0; g < KSPLIT; ++g) s += partial[(size_t)g * B_SZ * LCH + i];
    const int o = i % LCH;
    out[i] = s + b_out[o];
}

extern "C" void kernel_launch(void* const* d_in, const int* in_sizes, int n_in,
                              void* d_out, int out_size, void* d_ws, size_t ws_size,
                              hipStream_t stream)
{
    const int*   idx        = (const int*)  d_in[0];
    const float* eps        = (const float*)d_in[1];
    const float* h0         = (const float*)d_in[2];
    const float* c0         = (const float*)d_in[3];
    const float* mean_table = (const float*)d_in[4];
    const float* var_table  = (const float*)d_in[5];
    const float* W_ih       = (const float*)d_in[6];
    const float* W_hh       = (const float*)d_in[7];
    const float* g_ih       = (const float*)d_in[8];
    const float* bln_ih     = (const float*)d_in[9];
    const float* g_hh       = (const float*)d_in[10];
    const float* bln_hh     = (const float*)d_in[11];
    const float* g_c        = (const float*)d_in[12];
    const float* bln_c      = (const float*)d_in[13];
    const float* W_out      = (const float*)d_in[14];
    const float* b_out      = (const float*)d_in[15];
    float* out = (float*)d_out;

    unsigned short* hs = (unsigned short*)d_ws;                       // [2048][9600] bf16
    float* partial = (float*)((char*)d_ws + (size_t)B_SZ * KK * 2);   // [16][2048][150] f32

    const size_t need = (size_t)B_SZ * KK * 2 + (size_t)KSPLIT * B_SZ * LCH * 4;
    if (ws_size < need) return;

    lstm_kernel<<<B_SZ, 256, 0, stream>>>(idx, eps, h0, c0, mean_table, var_table,
                                          W_ih, W_hh, g_ih, bln_ih, g_hh, bln_hh,
                                          g_c, bln_c, hs);
    gemm_kernel<<<dim3(B_SZ / 64, KSPLIT), 256, 0, stream>>>(hs, W_out, partial);
    reduce_kernel<<<(B_SZ * LCH) / 256, 256, 0, stream>>>(partial, b_out, out);
}

// Round 2
// 967.053 us; speedup vs baseline: 1.2910x; 1.2910x over previous
//
#include <hip/hip_runtime.h>
#include <hip/hip_bf16.h>

#define LN_EPS 1e-5f
#define B_SZ 2048
#define LCH 150
#define EE 16
#define HH 64
#define G4 256
#define KK 9600
#define KSPLIT 16

__device__ __forceinline__ float bf2f(unsigned short u) {
    return __uint_as_float(((unsigned int)u) << 16);
}
__device__ __forceinline__ unsigned short f2bf(float f) {
    unsigned int u = __float_as_uint(f);
    unsigned int r = (u + 0x7FFFu + ((u >> 16) & 1u)) >> 16;
    return (unsigned short)r;
}
__device__ __forceinline__ float rcpf(float x) { return __builtin_amdgcn_rcpf(x); }
__device__ __forceinline__ float rsqf(float x) { return __builtin_amdgcn_rsqf(x); }
__device__ __forceinline__ float rlane(float v, int j) {
    return __int_as_float(__builtin_amdgcn_readlane(__float_as_int(v), j));
}

template<int CTRL, int RM>
__device__ __forceinline__ float dppadd(float x) {
    int y = __builtin_amdgcn_update_dpp(0, __float_as_int(x), CTRL, RM, 0xf, true);
    return x + __int_as_float(y);
}
// 64-lane sum; lane 63 holds the total afterwards.
__device__ __forceinline__ float wave_red(float x) {
    x = dppadd<0x111, 0xf>(x);   // row_shr:1
    x = dppadd<0x112, 0xf>(x);   // row_shr:2
    x = dppadd<0x114, 0xf>(x);   // row_shr:4
    x = dppadd<0x118, 0xf>(x);   // row_shr:8
    x = dppadd<0x142, 0xa>(x);   // row_bcast:15 -> rows 1,3
    x = dppadd<0x143, 0xc>(x);   // row_bcast:31 -> rows 2,3
    return x;
}

// One block = one batch row. Thread g owns gate g (wave w = gate-type w, lane = h-index).
// W rows in registers; h broadcast via v_readlane (VALU), LN reduces via DPP (VALU).
// Phase3 (c/h update) computed redundantly by all 4 waves -> h stays in registers,
// only 2 barriers/step, no LDS h round-trip.
__global__ __launch_bounds__(256, 4)
void lstm_kernel(const int* __restrict__ idx, const float* __restrict__ eps,
                 const float* __restrict__ h0, const float* __restrict__ c0,
                 const float* __restrict__ mean_table, const float* __restrict__ var_table,
                 const float* __restrict__ W_ih, const float* __restrict__ W_hh,
                 const float* __restrict__ g_ih, const float* __restrict__ bln_ih,
                 const float* __restrict__ g_hh, const float* __restrict__ bln_hh,
                 const float* __restrict__ g_c, const float* __restrict__ bln_c,
                 unsigned short* __restrict__ hs_out)
{
    const int b = blockIdx.x;
    const int tid = threadIdx.x;
    const int lane = tid & 63;
    const int wid = tid >> 6;

    __shared__ float x_lds[LCH * EE];
    __shared__ float act_lds[G4];
    __shared__ float red_lds[16];

    float wih[EE];
    {
        const float4* p = (const float4*)(W_ih + tid * EE);
        #pragma unroll
        for (int q = 0; q < 4; ++q) {
            float4 v = p[q];
            wih[4*q+0] = v.x; wih[4*q+1] = v.y; wih[4*q+2] = v.z; wih[4*q+3] = v.w;
        }
    }
    float whh[HH];
    {
        const float4* p = (const float4*)(W_hh + tid * HH);
        #pragma unroll
        for (int q = 0; q < 16; ++q) {
            float4 v = p[q];
            whh[4*q+0] = v.x; whh[4*q+1] = v.y; whh[4*q+2] = v.z; whh[4*q+3] = v.w;
        }
    }
    const float gih = g_ih[tid];
    const float ghh = g_hh[tid];
    const float bsum = bln_ih[tid] + bln_hh[tid];

    // fused embedding gather + reparameterization into LDS (x is loop-invariant)
    if (tid < LCH) {
        const int id = idx[b * LCH + tid];
        const float4* mp = (const float4*)(mean_table + (size_t)id * EE);
        const float4* vp = (const float4*)(var_table + (size_t)id * EE);
        const float4* ep = (const float4*)(eps + ((size_t)b * LCH + tid) * EE);
        float4* xp = (float4*)(x_lds + tid * EE);
        #pragma unroll
        for (int q = 0; q < 4; ++q) {
            float4 m = mp[q], v = vp[q], e = ep[q], r;
            r.x = e.x * __expf(0.5f * v.x) + m.x;
            r.y = e.y * __expf(0.5f * v.y) + m.y;
            r.z = e.z * __expf(0.5f * v.z) + m.z;
            r.w = e.w * __expf(0.5f * v.w) + m.w;
            xp[q] = r;
        }
    }
    // every wave holds a full copy of the recurrent state (lane j owns index j)
    float h_cur = h0[b * HH + lane];
    float c_reg = c0[b * HH + lane];
    const float gc = g_c[lane];
    const float bc = bln_c[lane];
    unsigned short* hp = hs_out + (size_t)b * KK + lane;
    __syncthreads();

    for (int t = 0; t < LCH; ++t) {
        // ---- phase 1: gate pre-activations + LN-256 partial sums ----
        float a_ih;
        {
            const float4* xp = (const float4*)(x_lds + t * EE);
            float4 x0 = xp[0], x1 = xp[1], x2 = xp[2], x3 = xp[3];
            float p0 = x0.x*wih[0] + x0.y*wih[1] + x0.z*wih[2] + x0.w*wih[3];
            float p1 = x1.x*wih[4] + x1.y*wih[5] + x1.z*wih[6] + x1.w*wih[7];
            float p2 = x2.x*wih[8] + x2.y*wih[9] + x2.z*wih[10] + x2.w*wih[11];
            float p3 = x3.x*wih[12] + x3.y*wih[13] + x3.z*wih[14] + x3.w*wih[15];
            a_ih = (p0 + p1) + (p2 + p3);
        }
        float ah0 = 0.f, ah1 = 0.f, ah2 = 0.f, ah3 = 0.f;
        #pragma unroll
        for (int j = 0; j < HH; j += 4) {
            ah0 = fmaf(whh[j+0], rlane(h_cur, j+0), ah0);
            ah1 = fmaf(whh[j+1], rlane(h_cur, j+1), ah1);
            ah2 = fmaf(whh[j+2], rlane(h_cur, j+2), ah2);
            ah3 = fmaf(whh[j+3], rlane(h_cur, j+3), ah3);
        }
        const float a_hh = (ah0 + ah1) + (ah2 + ah3);

        float s0 = wave_red(a_ih);
        float s1 = wave_red(a_ih * a_ih);
        float s2 = wave_red(a_hh);
        float s3 = wave_red(a_hh * a_hh);
        if (lane == 63) ((float4*)red_lds)[wid] = make_float4(s0, s1, s2, s3);
        __syncthreads();

        // ---- phase 2: LN-256 + gate activation ----
        float4 r0 = ((const float4*)red_lds)[0];
        float4 r1 = ((const float4*)red_lds)[1];
        float4 r2 = ((const float4*)red_lds)[2];
        float4 r3 = ((const float4*)red_lds)[3];
        const float inv = 1.f / 256.f;
        float m_ih = (r0.x + r1.x + r2.x + r3.x) * inv;
        float q_ih = (r0.y + r1.y + r2.y + r3.y) * inv;
        float m_hh = (r0.z + r1.z + r2.z + r3.z) * inv;
        float q_hh = (r0.w + r1.w + r2.w + r3.w) * inv;
        float rs_ih = rsqf(q_ih - m_ih * m_ih + LN_EPS);
        float rs_hh = rsqf(q_hh - m_hh * m_hh + LN_EPS);
        float gate = (a_ih - m_ih) * rs_ih * gih + (a_hh - m_hh) * rs_hh * ghh + bsum;
        // wave 0:i 1:f 3:o -> sigmoid; wave 2:g -> tanh (wave-uniform branch)
        float act;
        if (wid == 2) {
            act = 2.f * rcpf(1.f + __expf(-2.f * gate)) - 1.f;
        } else {
            act = rcpf(1.f + __expf(-gate));
        }
        act_lds[tid] = act;
        __syncthreads();

        // ---- phase 3 (all waves, redundant): c/h update + LN-64 ----
        float iv = act_lds[lane];
        float fv = act_lds[HH + lane];
        float gv = act_lds[2 * HH + lane];
        float ov = act_lds[3 * HH + lane];
        c_reg = fv * c_reg + iv * gv;
        float t0 = wave_red(c_reg);
        float t1 = wave_red(c_reg * c_reg);
        const float inv64 = 1.f / 64.f;
        float mc = rlane(t0, 63) * inv64;
        float qc = rlane(t1, 63) * inv64;
        float lnc = (c_reg - mc) * rsqf(qc - mc * mc + LN_EPS) * gc + bc;
        float th = 2.f * rcpf(1.f + __expf(-2.f * lnc)) - 1.f;
        h_cur = ov * th;
        if (wid == 0) hp[t * HH] = f2bf(h_cur);
        // no barrier needed: next phase1 uses only registers + loop-invariant x_lds;
        // red_lds rewrite is fenced by B1, act_lds rewrite by B1+B2.
    }
}

// out_partial[seg][row][c] = partial dot over this segment's K-chunks
__global__ __launch_bounds__(256)
void gemm_kernel(const unsigned short* __restrict__ A, const float* __restrict__ W,
                 float* __restrict__ partial)
{
    const int mb = blockIdx.x;
    const int seg = blockIdx.y;
    const int tid = threadIdx.x;
    const int r = tid & 63;
    const int cgu = __builtin_amdgcn_readfirstlane(tid >> 6);  // 0..3, wave-uniform

    __shared__ float aT[64][64];   // aT[k][r]
    float acc[38];
    #pragma unroll
    for (int j = 0; j < 38; ++j) acc[j] = 0.f;

    const int row0 = mb * 64;
    const int c_start = seg * 9 + (seg < 6 ? seg : 6);
    const int nch = 9 + (seg < 6 ? 1 : 0);

    for (int ch = c_start; ch < c_start + nch; ++ch) {
        const int k0 = ch * 64;
        __syncthreads();
        #pragma unroll
        for (int n = 0; n < 4; ++n) {
            const int item = tid + n * 256;
            const int rr = item >> 4;
            const int q4 = item & 15;
            ushort4 hv = *(const ushort4*)(A + (size_t)(row0 + rr) * KK + k0 + q4 * 4);
            aT[q4 * 4 + 0][rr] = bf2f(hv.x);
            aT[q4 * 4 + 1][rr] = bf2f(hv.y);
            aT[q4 * 4 + 2][rr] = bf2f(hv.z);
            aT[q4 * 4 + 3][rr] = bf2f(hv.w);
        }
        __syncthreads();
        #pragma unroll 2
        for (int k4 = 0; k4 < 16; ++k4) {
            const float a0 = aT[k4 * 4 + 0][r];
            const float a1 = aT[k4 * 4 + 1][r];
            const float a2 = aT[k4 * 4 + 2][r];
            const float a3 = aT[k4 * 4 + 3][r];
            #pragma unroll
            for (int j = 0; j < 38; ++j) {
                int c = cgu * 38 + j; c = c < 150 ? c : 149;
                const float4 bv = *(const float4*)(W + (size_t)c * KK + k0 + k4 * 4);
                acc[j] = fmaf(a0, bv.x, acc[j]);
                acc[j] = fmaf(a1, bv.y, acc[j]);
                acc[j] = fmaf(a2, bv.z, acc[j]);
                acc[j] = fmaf(a3, bv.w, acc[j]);
            }
        }
    }
    float* po = partial + ((size_t)seg * B_SZ + row0 + r) * 150;
    #pragma unroll
    for (int j = 0; j < 38; ++j) {
        const int c = cgu * 38 + j;
        if (c < 150) po[c] = acc[j];
    }
}

__global__ __launch_bounds__(256)
void reduce_kernel(const float* __restrict__ partial, const float* __restrict__ b_out,
                   float* __restrict__ out)
{
    const int i = blockIdx.x * 256 + threadIdx.x;
    if (i >= B_SZ * LCH) return;
    float s = 0.f;
    #pragma unroll
    for (int g = 0; g < KSPLIT; ++g) s += partial[(size_t)g * B_SZ * LCH + i];
    const int o = i % LCH;
    out[i] = s + b_out[o];
}

extern "C" void kernel_launch(void* const* d_in, const int* in_sizes, int n_in,
                              void* d_out, int out_size, void* d_ws, size_t ws_size,
                              hipStream_t stream)
{
    const int*   idx        = (const int*)  d_in[0];
    const float* eps        = (const float*)d_in[1];
    const float* h0         = (const float*)d_in[2];
    const float* c0         = (const float*)d_in[3];
    const float* mean_table = (const float*)d_in[4];
    const float* var_table  = (const float*)d_in[5];
    const float* W_ih       = (const float*)d_in[6];
    const float* W_hh       = (const float*)d_in[7];
    const float* g_ih       = (const float*)d_in[8];
    const float* bln_ih     = (const float*)d_in[9];
    const float* g_hh       = (const float*)d_in[10];
    const float* bln_hh     = (const float*)d_in[11];
    const float* g_c        = (const float*)d_in[12];
    const float* bln_c      = (const float*)d_in[13];
    const float* W_out      = (const float*)d_in[14];
    const float* b_out      = (const float*)d_in[15];
    float* out = (float*)d_out;

    unsigned short* hs = (unsigned short*)d_ws;                       // [2048][9600] bf16
    float* partial = (float*)((char*)d_ws + (size_t)B_SZ * KK * 2);   // [16][2048][150] f32

    const size_t need = (size_t)B_SZ * KK * 2 + (size_t)KSPLIT * B_SZ * LCH * 4;
    if (ws_size < need) return;

    lstm_kernel<<<B_SZ, 256, 0, stream>>>(idx, eps, h0, c0, mean_table, var_table,
                                          W_ih, W_hh, g_ih, bln_ih, g_hh, bln_hh,
                                          g_c, bln_c, hs);
    gemm_kernel<<<dim3(B_SZ / 64, KSPLIT), 256, 0, stream>>>(hs, W_out, partial);
    reduce_kernel<<<(B_SZ * LCH) / 256, 256, 0, stream>>>(partial, b_out, out);
}

// Round 4
// 540.982 us; speedup vs baseline: 2.3077x; 1.7876x over previous
//
#include <hip/hip_runtime.h>
#include <hip/hip_bf16.h>

#define LN_EPS 1e-5f
#define B_SZ 2048
#define LCH 150
#define HH 64
#define KK 9600
#define NSEG 12
#define KPS 800          // K per GEMM segment (25 k32-steps)
#define NPAD 160

typedef __attribute__((ext_vector_type(8))) short bf16x8;
typedef __attribute__((ext_vector_type(4))) float f32x4;

__device__ __forceinline__ float bf2f_lo(unsigned int u) {
    return __uint_as_float(u << 16);
}
__device__ __forceinline__ float bf2f_hi(unsigned int u) {
    return __uint_as_float(u & 0xffff0000u);
}
// packed RNE f32->bf16 pair: low16 = bf(a), high16 = bf(b)
__device__ __forceinline__ unsigned int cvtpk(float a, float b) {
    unsigned int r;
    asm("v_cvt_pk_bf16_f32 %0, %1, %2" : "=v"(r) : "v"(a), "v"(b));
    return r;
}
__device__ __forceinline__ float rcpf(float x) { return __builtin_amdgcn_rcpf(x); }
__device__ __forceinline__ float rsqf(float x) { return __builtin_amdgcn_rsqf(x); }

template<int CTRL>
__device__ __forceinline__ float dppadd16(float x) {
    int y = __builtin_amdgcn_update_dpp(0, __float_as_int(x), CTRL, 0xf, 0xf, true);
    return x + __int_as_float(y);
}
// sum within each 16-lane group (all lanes get the sum)
__device__ __forceinline__ float red16(float x) {
    x = dppadd16<0xB1>(x);   // quad_perm 1,0,3,2
    x = dppadd16<0x4E>(x);   // quad_perm 2,3,0,1
    x = dppadd16<0x141>(x);  // row_half_mirror
    x = dppadd16<0x140>(x);  // row_mirror
    return x;
}

// split 8 consecutive floats into 3-way bf16 fragments (hi+mid+lo ~ 2^-24 rel)
__device__ __forceinline__ void split3_8(const float* p, bf16x8* H, bf16x8* M, bf16x8* L) {
    union { bf16x8 v; unsigned int u[4]; } h_, m_, l_;
    #pragma unroll
    for (int q = 0; q < 4; ++q) {
        float a = p[2 * q], b = p[2 * q + 1];
        unsigned int hu = cvtpk(a, b);
        float da = a - bf2f_lo(hu), db = b - bf2f_hi(hu);
        unsigned int mu_ = cvtpk(da, db);
        float ea = da - bf2f_lo(mu_), eb = db - bf2f_hi(mu_);
        unsigned int lu = cvtpk(ea, eb);
        h_.u[q] = hu; m_.u[q] = mu_; l_.u[q] = lu;
    }
    *H = h_.v; *M = m_.v; *L = l_.v;
}

// rep = eps*exp(0.5*logvar)+mu, fp32, layout [t][b][e]
__global__ __launch_bounds__(256)
void prep_kernel(const int* __restrict__ idx, const float* __restrict__ eps,
                 const float* __restrict__ mean_table, const float* __restrict__ var_table,
                 float* __restrict__ rep)
{
    const int gid = blockIdx.x * 256 + threadIdx.x;      // t*2048 + b
    const int t = gid >> 11, b = gid & 2047;
    const int id = idx[b * LCH + t];
    const float4* mp = (const float4*)(mean_table + (size_t)id * 16);
    const float4* vp = (const float4*)(var_table + (size_t)id * 16);
    const float4* ep = (const float4*)(eps + ((size_t)b * LCH + t) * 16);
    float4* dp = (float4*)(rep + (size_t)gid * 16);
    #pragma unroll
    for (int q = 0; q < 4; ++q) {
        float4 m = mp[q], v = vp[q], e = ep[q], r;
        r.x = e.x * __expf(0.5f * v.x) + m.x;
        r.y = e.y * __expf(0.5f * v.y) + m.y;
        r.z = e.z * __expf(0.5f * v.z) + m.z;
        r.w = e.w * __expf(0.5f * v.w) + m.w;
        dp[q] = r;
    }
}

// 2-way split of W_out into bf16 hi/lo, rows 150..159 zero-padded
__global__ __launch_bounds__(256)
void wsplit_kernel(const float* __restrict__ W,
                   unsigned short* __restrict__ Whi, unsigned short* __restrict__ Wlo)
{
    const int gid = blockIdx.x * 256 + threadIdx.x;      // 160 * 1200
    const int row = gid / 1200;
    const int k8 = (gid - row * 1200) * 8;
    uint4 Hv = make_uint4(0, 0, 0, 0), Lv = Hv;
    if (row < 150) {
        const float* p = W + (size_t)row * KK + k8;
        unsigned int hu[4], lu[4];
        #pragma unroll
        for (int q = 0; q < 4; ++q) {
            float a = p[2 * q], b = p[2 * q + 1];
            unsigned int h = cvtpk(a, b);
            float da = a - bf2f_lo(h), db = b - bf2f_hi(h);
            hu[q] = h; lu[q] = cvtpk(da, db);
        }
        Hv = make_uint4(hu[0], hu[1], hu[2], hu[3]);
        Lv = make_uint4(lu[0], lu[1], lu[2], lu[3]);
    }
    *(uint4*)(Whi + (size_t)row * KK + k8) = Hv;
    *(uint4*)(Wlo + (size_t)row * KK + k8) = Lv;
}

// MFMA LSTM, 3-way-split precision (~2^-24 rel in-loop).
// Block = 16 batch rows, 4 waves; tile tn = gate type; j = w*16+lane16 = hidden idx.
__global__ __launch_bounds__(256, 1)
void lstm_kernel(const float* __restrict__ h0, const float* __restrict__ c0,
                 const float* __restrict__ W_ih, const float* __restrict__ W_hh,
                 const float* __restrict__ g_ih, const float* __restrict__ bln_ih,
                 const float* __restrict__ g_hh, const float* __restrict__ bln_hh,
                 const float* __restrict__ g_c, const float* __restrict__ bln_c,
                 const float* __restrict__ rep,
                 unsigned short* __restrict__ hs_out)
{
    const int tid = threadIdx.x;
    const int lane16 = tid & 15;
    const int lgrp = (tid >> 4) & 3;
    const int w = tid >> 6;
    const int row0 = blockIdx.x * 16;
    const int j = w * 16 + lane16;
    const bool grp01 = (lgrp < 2);

    __shared__ unsigned int h_hm[16 * 68];   // hi | mid<<16
    __shared__ unsigned int h_lo[16 * 68];   // lo in low 16
    __shared__ float st1[4][4][4][4];        // [lgrp][r][w][(s_hh,q_hh,s_ih,q_ih)]
    __shared__ float st2[4][4][4][2];        // [lgrp][r][w][(s_c,q_c)]

    // ---- static weight fragments ----
    bf16x8 whi[4][2], wmid[4][2], wlo[4][2];   // W_hh 3-way, per K-half c
    bf16x8 bi1[4], bi2[4], bi3[4];             // W_ih packed K=32 frags
    float gihc[4], ghhc[4], bsc[4];
    #pragma unroll
    for (int tn = 0; tn < 4; ++tn) {
        const int n = tn * 64 + j;
        #pragma unroll
        for (int c = 0; c < 2; ++c)
            split3_8(W_hh + n * 64 + c * 32 + lgrp * 8, &whi[tn][c], &wmid[tn][c], &wlo[tn][c]);
        bf16x8 h8, m8, l8;
        split3_8(W_ih + n * 16 + (lgrp & 1) * 8, &h8, &m8, &l8);
        bi1[tn] = grp01 ? h8 : m8;   // [Whi | Wmid]
        bi2[tn] = grp01 ? m8 : h8;   // [Wmid | Whi]
        bi3[tn] = grp01 ? l8 : h8;   // [Wlo | Whi]
        gihc[tn] = g_ih[n];
        ghhc[tn] = g_hh[n];
        bsc[tn] = bln_ih[n] + bln_hh[n];
    }
    const float gcc = g_c[j], bcc = bln_c[j];

    // ---- state init: c fp32 in regs, h 3-way split in LDS ----
    float c_reg[4];
    #pragma unroll
    for (int r = 0; r < 4; ++r) {
        const int row = lgrp * 4 + r;
        c_reg[r] = c0[(size_t)(row0 + row) * HH + j];
        float hv = h0[(size_t)(row0 + row) * HH + j];
        unsigned int t0 = cvtpk(hv, hv);
        float d = hv - bf2f_lo(t0);
        unsigned int hm = cvtpk(hv, d);
        float e = d - bf2f_hi(hm);
        h_hm[row * 68 + j] = hm;
        h_lo[row * 68 + j] = cvtpk(e, e) & 0xffffu;
    }

    // x prefetch (fp32, [t][b][e])
    const size_t xbase = (size_t)(row0 + lane16) * 16 + (lgrp & 1) * 8;
    float4 xc0 = *(const float4*)(rep + xbase);
    float4 xc1 = *(const float4*)(rep + xbase + 4);
    __syncthreads();

    const float INV256 = 1.f / 256.f, INV64 = 1.f / 64.f;

    for (int t = 0; t < LCH; ++t) {
        // ---- x 3-way split -> packed A-frags A1=[hi|mid], A2=[hi|lo] ----
        union { bf16x8 v; unsigned int u[4]; } A1u, A2u;
        {
            float xa[8] = {xc0.x, xc0.y, xc0.z, xc0.w, xc1.x, xc1.y, xc1.z, xc1.w};
            #pragma unroll
            for (int q = 0; q < 4; ++q) {
                float a = xa[2 * q], b = xa[2 * q + 1];
                unsigned int hu = cvtpk(a, b);
                float da = a - bf2f_lo(hu), db = b - bf2f_hi(hu);
                unsigned int mu_ = cvtpk(da, db);
                float ea = da - bf2f_lo(mu_), eb = db - bf2f_hi(mu_);
                unsigned int lu = cvtpk(ea, eb);
                A1u.u[q] = grp01 ? hu : mu_;
                A2u.u[q] = grp01 ? hu : lu;
            }
        }
        {
            const int tpf = (t + 1 < LCH) ? t + 1 : LCH - 1;
            xc0 = *(const float4*)(rep + (size_t)tpf * 2048 * 16 + xbase);
            xc1 = *(const float4*)(rep + (size_t)tpf * 2048 * 16 + xbase + 4);
        }

        f32x4 acc_hh[4], acc_ih[4];
        #pragma unroll
        for (int tn = 0; tn < 4; ++tn) { acc_hh[tn] = (f32x4)0.f; acc_ih[tn] = (f32x4)0.f; }

        // ---- ih: 3 packed MFMAs per tile (6 term-products) ----
        #pragma unroll
        for (int tn = 0; tn < 4; ++tn)
            acc_ih[tn] = __builtin_amdgcn_mfma_f32_16x16x32_bf16(A1u.v, bi1[tn], acc_ih[tn], 0, 0, 0);
        #pragma unroll
        for (int tn = 0; tn < 4; ++tn)
            acc_ih[tn] = __builtin_amdgcn_mfma_f32_16x16x32_bf16(A1u.v, bi2[tn], acc_ih[tn], 0, 0, 0);
        #pragma unroll
        for (int tn = 0; tn < 4; ++tn)
            acc_ih[tn] = __builtin_amdgcn_mfma_f32_16x16x32_bf16(A2u.v, bi3[tn], acc_ih[tn], 0, 0, 0);

        // ---- hh: 6 passes per K-half ----
        #pragma unroll
        for (int c = 0; c < 2; ++c) {
            const unsigned int* hp = &h_hm[lane16 * 68 + c * 32 + lgrp * 8];
            uint4 pa = *(const uint4*)hp;
            uint4 pb = *(const uint4*)(hp + 4);
            const unsigned int* lp = &h_lo[lane16 * 68 + c * 32 + lgrp * 8];
            uint4 qa = *(const uint4*)lp;
            uint4 qb = *(const uint4*)(lp + 4);
            union { bf16x8 v; unsigned int u[4]; } Ahi, Amid, Alo;
            Ahi.u[0] = (pa.x & 0xffffu) | (pa.y << 16);
            Ahi.u[1] = (pa.z & 0xffffu) | (pa.w << 16);
            Ahi.u[2] = (pb.x & 0xffffu) | (pb.y << 16);
            Ahi.u[3] = (pb.z & 0xffffu) | (pb.w << 16);
            Amid.u[0] = (pa.x >> 16) | (pa.y & 0xffff0000u);
            Amid.u[1] = (pa.z >> 16) | (pa.w & 0xffff0000u);
            Amid.u[2] = (pb.x >> 16) | (pb.y & 0xffff0000u);
            Amid.u[3] = (pb.z >> 16) | (pb.w & 0xffff0000u);
            Alo.u[0] = (qa.x & 0xffffu) | (qa.y << 16);
            Alo.u[1] = (qa.z & 0xffffu) | (qa.w << 16);
            Alo.u[2] = (qb.x & 0xffffu) | (qb.y << 16);
            Alo.u[3] = (qb.z & 0xffffu) | (qb.w << 16);
            #pragma unroll
            for (int tn = 0; tn < 4; ++tn)
                acc_hh[tn] = __builtin_amdgcn_mfma_f32_16x16x32_bf16(Ahi.v, whi[tn][c], acc_hh[tn], 0, 0, 0);
            #pragma unroll
            for (int tn = 0; tn < 4; ++tn)
                acc_hh[tn] = __builtin_amdgcn_mfma_f32_16x16x32_bf16(Ahi.v, wmid[tn][c], acc_hh[tn], 0, 0, 0);
            #pragma unroll
            for (int tn = 0; tn < 4; ++tn)
                acc_hh[tn] = __builtin_amdgcn_mfma_f32_16x16x32_bf16(Amid.v, whi[tn][c], acc_hh[tn], 0, 0, 0);
            #pragma unroll
            for (int tn = 0; tn < 4; ++tn)
                acc_hh[tn] = __builtin_amdgcn_mfma_f32_16x16x32_bf16(Amid.v, wmid[tn][c], acc_hh[tn], 0, 0, 0);
            #pragma unroll
            for (int tn = 0; tn < 4; ++tn)
                acc_hh[tn] = __builtin_amdgcn_mfma_f32_16x16x32_bf16(Ahi.v, wlo[tn][c], acc_hh[tn], 0, 0, 0);
            #pragma unroll
            for (int tn = 0; tn < 4; ++tn)
                acc_hh[tn] = __builtin_amdgcn_mfma_f32_16x16x32_bf16(Alo.v, whi[tn][c], acc_hh[tn], 0, 0, 0);
        }

        // ---- LN-256 stats ----
        float sh[4], qh[4], si[4], qi[4];
        #pragma unroll
        for (int r = 0; r < 4; ++r) {
            float a0 = acc_hh[0][r], a1 = acc_hh[1][r], a2 = acc_hh[2][r], a3 = acc_hh[3][r];
            sh[r] = red16((a0 + a1) + (a2 + a3));
            qh[r] = red16(a0 * a0 + a1 * a1 + a2 * a2 + a3 * a3);
            float b0 = acc_ih[0][r], b1 = acc_ih[1][r], b2 = acc_ih[2][r], b3 = acc_ih[3][r];
            si[r] = red16((b0 + b1) + (b2 + b3));
            qi[r] = red16(b0 * b0 + b1 * b1 + b2 * b2 + b3 * b3);
        }
        if (lane16 == 0) {
            #pragma unroll
            for (int r = 0; r < 4; ++r) {
                f32x4 v; v[0] = sh[r]; v[1] = qh[r]; v[2] = si[r]; v[3] = qi[r];
                *(f32x4*)&st1[lgrp][r][w][0] = v;
            }
        }
        __syncthreads();   // B1

        float mh[4], rsh[4], mi[4], rsi[4];
        #pragma unroll
        for (int r = 0; r < 4; ++r) {
            f32x4 v0 = *(const f32x4*)&st1[lgrp][r][0][0];
            f32x4 v1 = *(const f32x4*)&st1[lgrp][r][1][0];
            f32x4 v2 = *(const f32x4*)&st1[lgrp][r][2][0];
            f32x4 v3 = *(const f32x4*)&st1[lgrp][r][3][0];
            f32x4 s = (v0 + v1) + (v2 + v3);
            float m1 = s[0] * INV256;
            mh[r] = m1; rsh[r] = rsqf(s[1] * INV256 - m1 * m1 + LN_EPS);
            float m2 = s[2] * INV256;
            mi[r] = m2; rsi[r] = rsqf(s[3] * INV256 - m2 * m2 + LN_EPS);
        }

        float act[4][4];
        #pragma unroll
        for (int tn = 0; tn < 4; ++tn) {
            #pragma unroll
            for (int r = 0; r < 4; ++r) {
                float g = (acc_hh[tn][r] - mh[r]) * rsh[r] * ghhc[tn]
                        + (acc_ih[tn][r] - mi[r]) * rsi[r] * gihc[tn] + bsc[tn];
                if (tn == 2) act[tn][r] = 2.f * rcpf(1.f + __expf(-2.f * g)) - 1.f;
                else         act[tn][r] = rcpf(1.f + __expf(-g));
            }
        }

        // ---- c update + LN-64 ----
        float sc[4], qc[4];
        #pragma unroll
        for (int r = 0; r < 4; ++r) {
            c_reg[r] = act[1][r] * c_reg[r] + act[0][r] * act[2][r];
            sc[r] = red16(c_reg[r]);
            qc[r] = red16(c_reg[r] * c_reg[r]);
        }
        if (lane16 == 0) {
            #pragma unroll
            for (int r = 0; r < 4; ++r) {
                st2[lgrp][r][w][0] = sc[r];
                st2[lgrp][r][w][1] = qc[r];
            }
        }
        __syncthreads();   // B2

        #pragma unroll
        for (int r = 0; r < 4; ++r) {
            float Sc = st2[lgrp][r][0][0] + st2[lgrp][r][1][0]
                     + st2[lgrp][r][2][0] + st2[lgrp][r][3][0];
            float Qc = st2[lgrp][r][0][1] + st2[lgrp][r][1][1]
                     + st2[lgrp][r][2][1] + st2[lgrp][r][3][1];
            float mc = Sc * INV64;
            float rsc = rsqf(Qc * INV64 - mc * mc + LN_EPS);
            float lnc = (c_reg[r] - mc) * rsc * gcc + bcc;
            float th = 2.f * rcpf(1.f + __expf(-2.f * lnc)) - 1.f;
            float h = act[3][r] * th;
            unsigned int t0 = cvtpk(h, h);
            float d = h - bf2f_lo(t0);
            unsigned int hm = cvtpk(h, d);
            float e = d - bf2f_hi(hm);
            const int row = lgrp * 4 + r;
            h_hm[row * 68 + j] = hm;
            h_lo[row * 68 + j] = cvtpk(e, e) & 0xffffu;
            hs_out[(size_t)(row0 + row) * KK + t * HH + j] = (unsigned short)(hm & 0xffffu);
        }
        __syncthreads();   // B3
    }
}

// MFMA output GEMM: out = hs(bf16) @ (Whi+Wlo)^T, K-split into NSEG partials
__global__ __launch_bounds__(256)
void gemm_kernel(const unsigned short* __restrict__ hs,
                 const unsigned short* __restrict__ Whi,
                 const unsigned short* __restrict__ Wlo,
                 float* __restrict__ partial)
{
    const int mb = blockIdx.x;       // 0..31
    const int seg = blockIdx.y;      // 0..NSEG-1
    const int tid = threadIdx.x;
    const int l = tid & 63;
    const int w = tid >> 6;
    const int lane16 = l & 15;
    const int lgrp = l >> 4;

    f32x4 acc[10];
    #pragma unroll
    for (int nt = 0; nt < 10; ++nt) acc[nt] = (f32x4)0.f;

    const int kstart = seg * KPS + lgrp * 8;
    const unsigned short* ap = hs + (size_t)(mb * 64 + w * 16 + lane16) * KK + kstart;

    for (int s = 0; s < KPS / 32; ++s) {
        const int k = s * 32;
        union { bf16x8 v; uint4 u; } A;
        A.u = *(const uint4*)(ap + k);
        #pragma unroll
        for (int nt = 0; nt < 10; ++nt) {
            const size_t boff = (size_t)(nt * 16 + lane16) * KK + kstart + k;
            union { bf16x8 v; uint4 u; } Bh, Bl;
            Bh.u = *(const uint4*)(Whi + boff);
            Bl.u = *(const uint4*)(Wlo + boff);
            acc[nt] = __builtin_amdgcn_mfma_f32_16x16x32_bf16(A.v, Bh.v, acc[nt], 0, 0, 0);
            acc[nt] = __builtin_amdgcn_mfma_f32_16x16x32_bf16(A.v, Bl.v, acc[nt], 0, 0, 0);
        }
    }
    float* po = partial + ((size_t)seg * B_SZ + mb * 64 + w * 16 + lgrp * 4) * NPAD + lane16;
    #pragma unroll
    for (int nt = 0; nt < 10; ++nt)
        #pragma unroll
        for (int r = 0; r < 4; ++r)
            po[(size_t)r * NPAD + nt * 16] = acc[nt][r];
}

__global__ __launch_bounds__(256)
void reduce_kernel(const float* __restrict__ partial, const float* __restrict__ b_out,
                   float* __restrict__ out)
{
    const int i = blockIdx.x * 256 + threadIdx.x;   // row*150 + c
    const int row = i / 150;
    const int c = i - row * 150;
    float s = 0.f;
    #pragma unroll
    for (int g = 0; g < NSEG; ++g)
        s += partial[((size_t)g * B_SZ + row) * NPAD + c];
    out[i] = s + b_out[c];
}

extern "C" void kernel_launch(void* const* d_in, const int* in_sizes, int n_in,
                              void* d_out, int out_size, void* d_ws, size_t ws_size,
                              hipStream_t stream)
{
    const int*   idx        = (const int*)  d_in[0];
    const float* eps        = (const float*)d_in[1];
    const float* h0         = (const float*)d_in[2];
    const float* c0         = (const float*)d_in[3];
    const float* mean_table = (const float*)d_in[4];
    const float* var_table  = (const float*)d_in[5];
    const float* W_ih       = (const float*)d_in[6];
    const float* W_hh       = (const float*)d_in[7];
    const float* g_ih       = (const float*)d_in[8];
    const float* bln_ih     = (const float*)d_in[9];
    const float* g_hh       = (const float*)d_in[10];
    const float* bln_hh     = (const float*)d_in[11];
    const float* g_c        = (const float*)d_in[12];
    const float* bln_c      = (const float*)d_in[13];
    const float* W_out      = (const float*)d_in[14];
    const float* b_out      = (const float*)d_in[15];
    float* out = (float*)d_out;

    // ws layout:
    //   [0, 19.66MB):  rep fp32 [150][2048][16]  (later aliased by partial [12][2048][160] f32, 15.7MB)
    //   [19.66, 58.98): hs bf16 [2048][9600]
    //   [58.98, 62.05): Whi bf16 [160][9600]
    //   [62.05, 65.13): Wlo bf16 [160][9600]
    char* wsb = (char*)d_ws;
    const size_t rep_bytes = (size_t)LCH * B_SZ * 16 * 4;        // 19,660,800
    const size_t hs_bytes  = (size_t)B_SZ * KK * 2;              // 39,321,600
    const size_t w_bytes   = (size_t)NPAD * KK * 2;              //  3,072,000
    float* rep = (float*)wsb;
    float* partial = (float*)wsb;                                 // alias (disjoint in time)
    unsigned short* hs  = (unsigned short*)(wsb + rep_bytes);
    unsigned short* Whi = (unsigned short*)(wsb + rep_bytes + hs_bytes);
    unsigned short* Wlo = (unsigned short*)(wsb + rep_bytes + hs_bytes + w_bytes);

    const size_t need = rep_bytes + hs_bytes + 2 * w_bytes;
    if (ws_size < need) return;

    prep_kernel<<<(B_SZ * LCH) / 256, 256, 0, stream>>>(idx, eps, mean_table, var_table, rep);
    wsplit_kernel<<<(NPAD * KK / 8) / 256, 256, 0, stream>>>(W_out, Whi, Wlo);
    lstm_kernel<<<B_SZ / 16, 256, 0, stream>>>(h0, c0, W_ih, W_hh, g_ih, bln_ih,
                                               g_hh, bln_hh, g_c, bln_c, rep, hs);
    gemm_kernel<<<dim3(32, NSEG), 256, 0, stream>>>(hs, Whi, Wlo, partial);
    reduce_kernel<<<(B_SZ * LCH) / 256, 256, 0, stream>>>(partial, b_out, out);
}

// Round 5
// 496.915 us; speedup vs baseline: 2.5123x; 1.0887x over previous
//
#include <hip/hip_runtime.h>
#include <hip/hip_bf16.h>

#define LN_EPS 1e-5f
#define B_SZ 2048
#define LCH 150
#define HH 64
#define KK 9600
#define NSEG 12
#define KPS 800
#define NPAD 160
#define BB 8
#define RS 72
#define LSC 4096.0f
#define ISC (1.0f/4096.0f)

typedef __attribute__((ext_vector_type(8))) _Float16 f16x8;
typedef __attribute__((ext_vector_type(8))) short bf16x8;
typedef __attribute__((ext_vector_type(4))) float f32x4;

__device__ __forceinline__ float bf2f(unsigned short u) {
    return __uint_as_float(((unsigned int)u) << 16);
}
__device__ __forceinline__ unsigned short f2bf(float f) {
    unsigned int u = __float_as_uint(f);
    unsigned int r = (u + 0x7FFFu + ((u >> 16) & 1u)) >> 16;
    return (unsigned short)r;
}
__device__ __forceinline__ float bf2f_lo(unsigned int u) { return __uint_as_float(u << 16); }
__device__ __forceinline__ float bf2f_hi(unsigned int u) { return __uint_as_float(u & 0xffff0000u); }
__device__ __forceinline__ unsigned int cvtpk(float a, float b) {
    unsigned int r;
    asm("v_cvt_pk_bf16_f32 %0, %1, %2" : "=v"(r) : "v"(a), "v"(b));
    return r;
}
__device__ __forceinline__ float rcpf(float x) { return __builtin_amdgcn_rcpf(x); }
__device__ __forceinline__ float rsqf(float x) { return __builtin_amdgcn_rsqf(x); }

template<int CTRL>
__device__ __forceinline__ float dppadd16(float x) {
    int y = __builtin_amdgcn_update_dpp(0, __float_as_int(x), CTRL, 0xf, 0xf, true);
    return x + __int_as_float(y);
}
// sum within each 16-lane group (all lanes end with the sum)
__device__ __forceinline__ float red16(float x) {
    x = dppadd16<0xB1>(x);   // quad_perm 1,0,3,2
    x = dppadd16<0x4E>(x);   // quad_perm 2,3,0,1
    x = dppadd16<0x141>(x);  // row_half_mirror
    x = dppadd16<0x140>(x);  // row_mirror
    return x;
}

// -------- stats of W_ih: S = sum_n w_n w_n^T (16x16), cs = sum_n w_n --------
__global__ __launch_bounds__(256)
void wstat_kernel(const float* __restrict__ W_ih, float* __restrict__ Scs)
{
    const int tid = threadIdx.x;
    const int p = tid >> 4, q = tid & 15;
    float s = 0.f;
    for (int n = 0; n < 256; ++n)
        s += W_ih[n * 16 + p] * W_ih[n * 16 + q];
    Scs[p * 16 + q] = s;
    if (tid < 16) {
        float c = 0.f;
        for (int n = 0; n < 256; ++n) c += W_ih[n * 16 + tid];
        Scs[256 + tid] = c;
    }
}

// -------- prep: rep = eps*exp(0.5*logvar)+mu; fp16 limb A-frags + ih LN stats --------
__global__ __launch_bounds__(256)
void prep_kernel(const int* __restrict__ idx, const float* __restrict__ eps,
                 const float* __restrict__ mean_table, const float* __restrict__ var_table,
                 const float* __restrict__ Scs,
                 f16x8* __restrict__ repXf, float2* __restrict__ repS)
{
    const int gid = blockIdx.x * 256 + threadIdx.x;      // t*2048 + b
    const int t = gid >> 11, b = gid & 2047;
    const int id = idx[b * LCH + t];
    const float4* mp = (const float4*)(mean_table + (size_t)id * 16);
    const float4* vp = (const float4*)(var_table + (size_t)id * 16);
    const float4* ep = (const float4*)(eps + ((size_t)b * LCH + t) * 16);
    float x[16];
    #pragma unroll
    for (int q = 0; q < 4; ++q) {
        float4 m = mp[q], v = vp[q], e = ep[q];
        x[4*q+0] = e.x * __expf(0.5f * v.x) + m.x;
        x[4*q+1] = e.y * __expf(0.5f * v.y) + m.y;
        x[4*q+2] = e.z * __expf(0.5f * v.z) + m.z;
        x[4*q+3] = e.w * __expf(0.5f * v.w) + m.w;
    }
    // LN stats of x @ W_ih^T over 256 gates via precomputed S, cs
    float m1 = 0.f, qq = 0.f;
    #pragma unroll 4
    for (int p = 0; p < 16; ++p) {
        float sp = 0.f;
        #pragma unroll
        for (int q2 = 0; q2 < 16; ++q2) sp += Scs[p * 16 + q2] * x[q2];
        qq += x[p] * sp;
        m1 += Scs[256 + p] * x[p];
    }
    const float inv = 1.f / 256.f;
    m1 *= inv; qq *= inv;
    const float rs = rsqf(qq - m1 * m1 + LN_EPS);
    repS[gid] = make_float2(m1, rs);
    // fp16 limb frags: slot0=H(f0-7) slot1=H(f8-15) slot2=L'(f0-7) slot3=L'(f8-15)
    f16x8 H0, H1, L0, L1;
    #pragma unroll
    for (int f = 0; f < 8; ++f) {
        _Float16 h0_ = (_Float16)x[f];
        H0[f] = h0_; L0[f] = (_Float16)((x[f] - (float)h0_) * LSC);
        _Float16 h1_ = (_Float16)x[8 + f];
        H1[f] = h1_; L1[f] = (_Float16)((x[8 + f] - (float)h1_) * LSC);
    }
    f16x8* dst = repXf + (size_t)gid * 4;
    dst[0] = H0; dst[1] = H1; dst[2] = L0; dst[3] = L1;
}

// -------- 2-way bf16 split of W_out (rows 150..159 zero) --------
__global__ __launch_bounds__(256)
void wsplit_kernel(const float* __restrict__ W,
                   unsigned short* __restrict__ Whi, unsigned short* __restrict__ Wlo)
{
    const int gid = blockIdx.x * 256 + threadIdx.x;      // 160 * 1200
    const int row = gid / 1200;
    const int k8 = (gid - row * 1200) * 8;
    uint4 Hv = make_uint4(0, 0, 0, 0), Lv = Hv;
    if (row < 150) {
        const float* p = W + (size_t)row * KK + k8;
        unsigned int hu[4], lu[4];
        #pragma unroll
        for (int q = 0; q < 4; ++q) {
            float a = p[2 * q], b = p[2 * q + 1];
            unsigned int h = cvtpk(a, b);
            float da = a - bf2f_lo(h), db = b - bf2f_hi(h);
            hu[q] = h; lu[q] = cvtpk(da, db);
        }
        Hv = make_uint4(hu[0], hu[1], hu[2], hu[3]);
        Lv = make_uint4(lu[0], lu[1], lu[2], lu[3]);
    }
    *(uint4*)(Whi + (size_t)row * KK + k8) = Hv;
    *(uint4*)(Wlo + (size_t)row * KK + k8) = Lv;
}

// -------- MFMA LSTM: BB=8 rows/block, fp16 2-limb scaled, 32 MFMAs/wave/step --------
__global__ __launch_bounds__(256, 1)
void lstm_kernel(const float* __restrict__ h0, const float* __restrict__ c0,
                 const float* __restrict__ W_ih, const float* __restrict__ W_hh,
                 const float* __restrict__ g_ih, const float* __restrict__ bln_ih,
                 const float* __restrict__ g_hh, const float* __restrict__ bln_hh,
                 const float* __restrict__ g_c, const float* __restrict__ bln_c,
                 const f16x8* __restrict__ repXf, const float2* __restrict__ repS,
                 unsigned short* __restrict__ hs_out)
{
    const int tid = threadIdx.x;
    const int m = tid & 15;              // A-row / batch sub-row
    const int g = (tid >> 4) & 3;        // k-slice group / C row group
    const int w = tid >> 6;              // wave: j-slice
    const int row0 = blockIdx.x * BB;
    const int j = w * 16 + m;            // hidden index
    const bool g01 = (g < 2);

    __shared__ _Float16 hH[16 * RS];
    __shared__ _Float16 hL[16 * RS];
    __shared__ float2 st1[4][4][4];      // [g][r][w]
    __shared__ float2 st2[4][4][4];

    // ---- static weight fragments ----
    f16x8 WHf[4][2], WLf[4][2], Bi1[4], Bi2[4];
    float gihc[4], ghhc[4], bsc[4];
    #pragma unroll
    for (int tn = 0; tn < 4; ++tn) {
        const int n = tn * 64 + j;
        #pragma unroll
        for (int c = 0; c < 2; ++c) {
            const float* wp = W_hh + n * 64 + c * 32 + g * 8;
            #pragma unroll
            for (int q = 0; q < 8; ++q) {
                float v = wp[q];
                _Float16 h_ = (_Float16)v;
                WHf[tn][c][q] = h_;
                WLf[tn][c][q] = (_Float16)((v - (float)h_) * LSC);
            }
        }
        const float* ip = W_ih + n * 16 + (g & 1) * 8;
        #pragma unroll
        for (int q = 0; q < 8; ++q) {
            float v = ip[q];
            _Float16 h_ = (_Float16)v;
            _Float16 l_ = (_Float16)((v - (float)h_) * LSC);
            Bi1[tn][q] = g01 ? h_ : (_Float16)0.f;   // pass1: [WH | 0]   -> X_H*W_H
            Bi2[tn][q] = g01 ? l_ : h_;              // pass2: [WL'| WH]  -> H*L' + L'*H
        }
        gihc[tn] = g_ih[n];
        ghhc[tn] = g_hh[n];
        bsc[tn] = bln_ih[n] + bln_hh[n];
    }
    const float gcc = g_c[j], bcc = bln_c[j];

    // ---- state init ----
    const int crow = row0 + 4 * (g & 1);             // this thread's scalar rows (g<2 live)
    float c_reg[4];
    #pragma unroll
    for (int r = 0; r < 4; ++r) c_reg[r] = c0[(size_t)(crow + r) * HH + j];
    #pragma unroll
    for (int it = 0; it < 4; ++it) {
        const int s = tid + it * 256;
        const int rr = s >> 6, jj = s & 63;
        float hv = (rr < BB) ? h0[(size_t)(row0 + rr) * HH + jj] : 0.f;
        _Float16 Hh = (_Float16)hv;
        hH[rr * RS + jj] = Hh;
        hL[rr * RS + jj] = (_Float16)((hv - (float)Hh) * LSC);
    }

    // x / stats prefetch (t=0)
    const int rowx = row0 + (m < BB ? m : BB - 1);
    const int xoff = (g >> 1) * 2 + (g & 1);
    f16x8 AX = repXf[((size_t)rowx) * 4 + xoff];
    float4 mrsA = *(const float4*)&repS[crow];
    float4 mrsB = *(const float4*)&repS[crow + 2];
    __syncthreads();

    const float INV256 = 1.f / 256.f, INV64 = 1.f / 64.f;

    for (int t = 0; t < LCH; ++t) {
        // ---- A-frags (LDS, fragment-ready: no unpack) ----
        const f16x8 AH0 = *(const f16x8*)&hH[m * RS + g * 8];
        const f16x8 AH1 = *(const f16x8*)&hH[m * RS + 32 + g * 8];
        const f16x8 AL0 = *(const f16x8*)&hL[m * RS + g * 8];
        const f16x8 AL1 = *(const f16x8*)&hL[m * RS + 32 + g * 8];

        f32x4 a1h[4], a2h[4], a1i[4], a2i[4];
        #pragma unroll
        for (int tn = 0; tn < 4; ++tn) {
            a1h[tn] = (f32x4)0.f; a2h[tn] = (f32x4)0.f;
            a1i[tn] = (f32x4)0.f; a2i[tn] = (f32x4)0.f;
        }
        // hh: H*H -> a1h ; H*L' + L'*H -> a2h (scale 2^12)
        #pragma unroll
        for (int tn = 0; tn < 4; ++tn) {
            a1h[tn] = __builtin_amdgcn_mfma_f32_16x16x32_f16(AH0, WHf[tn][0], a1h[tn], 0, 0, 0);
            a1h[tn] = __builtin_amdgcn_mfma_f32_16x16x32_f16(AH1, WHf[tn][1], a1h[tn], 0, 0, 0);
        }
        #pragma unroll
        for (int tn = 0; tn < 4; ++tn) {
            a2h[tn] = __builtin_amdgcn_mfma_f32_16x16x32_f16(AH0, WLf[tn][0], a2h[tn], 0, 0, 0);
            a2h[tn] = __builtin_amdgcn_mfma_f32_16x16x32_f16(AH1, WLf[tn][1], a2h[tn], 0, 0, 0);
            a2h[tn] = __builtin_amdgcn_mfma_f32_16x16x32_f16(AL0, WHf[tn][0], a2h[tn], 0, 0, 0);
            a2h[tn] = __builtin_amdgcn_mfma_f32_16x16x32_f16(AL1, WHf[tn][1], a2h[tn], 0, 0, 0);
        }
        // ih: packed 2 passes
        #pragma unroll
        for (int tn = 0; tn < 4; ++tn) {
            a1i[tn] = __builtin_amdgcn_mfma_f32_16x16x32_f16(AX, Bi1[tn], a1i[tn], 0, 0, 0);
            a2i[tn] = __builtin_amdgcn_mfma_f32_16x16x32_f16(AX, Bi2[tn], a2i[tn], 0, 0, 0);
        }

        // ---- prefetch next step ----
        const int tp = (t + 1 < LCH) ? t + 1 : LCH - 1;
        const f16x8 AXn = repXf[((size_t)tp * 2048 + rowx) * 4 + xoff];
        const float4 mrsAn = *(const float4*)&repS[(size_t)tp * 2048 + crow];
        const float4 mrsBn = *(const float4*)&repS[(size_t)tp * 2048 + crow + 2];

        // ---- limb combine ----
        float ahh[4][4], aih[4][4];
        #pragma unroll
        for (int tn = 0; tn < 4; ++tn)
            #pragma unroll
            for (int r = 0; r < 4; ++r) {
                ahh[tn][r] = fmaf(a2h[tn][r], ISC, a1h[tn][r]);
                aih[tn][r] = fmaf(a2i[tn][r], ISC, a1i[tn][r]);
            }

        // ---- LN-256 stats (hh only; ih stats precomputed) ----
        #pragma unroll
        for (int r = 0; r < 4; ++r) {
            float s = (ahh[0][r] + ahh[1][r]) + (ahh[2][r] + ahh[3][r]);
            float qv = ahh[0][r]*ahh[0][r] + ahh[1][r]*ahh[1][r]
                     + ahh[2][r]*ahh[2][r] + ahh[3][r]*ahh[3][r];
            s = red16(s);
            qv = red16(qv);
            if (m == 0) st1[g][r][w] = make_float2(s, qv);
        }
        __syncthreads();   // B1

        float mh[4], rsh[4];
        #pragma unroll
        for (int r = 0; r < 4; ++r) {
            float2 u0 = st1[g][r][0], u1 = st1[g][r][1];
            float2 u2 = st1[g][r][2], u3 = st1[g][r][3];
            float S = (u0.x + u1.x) + (u2.x + u3.x);
            float Q = (u0.y + u1.y) + (u2.y + u3.y);
            float mm = S * INV256;
            mh[r] = mm;
            rsh[r] = rsqf(Q * INV256 - mm * mm + LN_EPS);
        }
        const float mi[4]  = {mrsA.x, mrsA.z, mrsB.x, mrsB.z};
        const float rsi[4] = {mrsA.y, mrsA.w, mrsB.y, mrsB.w};

        // ---- normalize + activations (tn: 0=i 1=f 2=g(tanh) 3=o) ----
        float act[4][4];
        #pragma unroll
        for (int tn = 0; tn < 4; ++tn)
            #pragma unroll
            for (int r = 0; r < 4; ++r) {
                float gate = (ahh[tn][r] - mh[r]) * rsh[r] * ghhc[tn]
                           + (aih[tn][r] - mi[r]) * rsi[r] * gihc[tn] + bsc[tn];
                if (tn == 2) act[tn][r] = 2.f * rcpf(1.f + __expf(-2.f * gate)) - 1.f;
                else         act[tn][r] = rcpf(1.f + __expf(-gate));
            }

        // ---- c update + LN-64 stats ----
        #pragma unroll
        for (int r = 0; r < 4; ++r) {
            c_reg[r] = act[1][r] * c_reg[r] + act[0][r] * act[2][r];
            float sc = red16(c_reg[r]);
            float qc = red16(c_reg[r] * c_reg[r]);
            if (m == 0) st2[g][r][w] = make_float2(sc, qc);
        }
        __syncthreads();   // B2

        #pragma unroll
        for (int r = 0; r < 4; ++r) {
            float2 u0 = st2[g][r][0], u1 = st2[g][r][1];
            float2 u2 = st2[g][r][2], u3 = st2[g][r][3];
            float Sc = (u0.x + u1.x) + (u2.x + u3.x);
            float Qc = (u0.y + u1.y) + (u2.y + u3.y);
            float mc = Sc * INV64;
            float rsc = rsqf(Qc * INV64 - mc * mc + LN_EPS);
            float lnc = (c_reg[r] - mc) * rsc * gcc + bcc;
            float th = 2.f * rcpf(1.f + __expf(-2.f * lnc)) - 1.f;
            float h = act[3][r] * th;
            if (g01) {
                const int lr = 4 * g + r;
                _Float16 Hh = (_Float16)h;
                hH[lr * RS + j] = Hh;
                hL[lr * RS + j] = (_Float16)((h - (float)Hh) * LSC);
                hs_out[(size_t)(row0 + lr) * KK + t * HH + j] = f2bf(h);
            }
        }
        __syncthreads();   // B3

        AX = AXn; mrsA = mrsAn; mrsB = mrsBn;
    }
}

// -------- MFMA output GEMM (bf16 2-limb W_out), K-split partials --------
__global__ __launch_bounds__(256)
void gemm_kernel(const unsigned short* __restrict__ hs,
                 const unsigned short* __restrict__ Whi,
                 const unsigned short* __restrict__ Wlo,
                 float* __restrict__ partial)
{
    const int mb = blockIdx.x;       // 0..31
    const int seg = blockIdx.y;      // 0..NSEG-1
    const int tid = threadIdx.x;
    const int l = tid & 63;
    const int w = tid >> 6;
    const int lane16 = l & 15;
    const int lgrp = l >> 4;

    f32x4 acc[10];
    #pragma unroll
    for (int nt = 0; nt < 10; ++nt) acc[nt] = (f32x4)0.f;

    const int kstart = seg * KPS + lgrp * 8;
    const unsigned short* ap = hs + (size_t)(mb * 64 + w * 16 + lane16) * KK + kstart;

    for (int s = 0; s < KPS / 32; ++s) {
        const int k = s * 32;
        union { bf16x8 v; uint4 u; } A;
        A.u = *(const uint4*)(ap + k);
        #pragma unroll
        for (int nt = 0; nt < 10; ++nt) {
            const size_t boff = (size_t)(nt * 16 + lane16) * KK + kstart + k;
            union { bf16x8 v; uint4 u; } Bh, Bl;
            Bh.u = *(const uint4*)(Whi + boff);
            Bl.u = *(const uint4*)(Wlo + boff);
            acc[nt] = __builtin_amdgcn_mfma_f32_16x16x32_bf16(A.v, Bh.v, acc[nt], 0, 0, 0);
            acc[nt] = __builtin_amdgcn_mfma_f32_16x16x32_bf16(A.v, Bl.v, acc[nt], 0, 0, 0);
        }
    }
    float* po = partial + ((size_t)seg * B_SZ + mb * 64 + w * 16 + lgrp * 4) * NPAD + lane16;
    #pragma unroll
    for (int nt = 0; nt < 10; ++nt)
        #pragma unroll
        for (int r = 0; r < 4; ++r)
            po[(size_t)r * NPAD + nt * 16] = acc[nt][r];
}

__global__ __launch_bounds__(256)
void reduce_kernel(const float* __restrict__ partial, const float* __restrict__ b_out,
                   float* __restrict__ out)
{
    const int i = blockIdx.x * 256 + threadIdx.x;   // row*150 + c
    const int row = i / 150;
    const int c = i - row * 150;
    float s = 0.f;
    #pragma unroll
    for (int g = 0; g < NSEG; ++g)
        s += partial[((size_t)g * B_SZ + row) * NPAD + c];
    out[i] = s + b_out[c];
}

extern "C" void kernel_launch(void* const* d_in, const int* in_sizes, int n_in,
                              void* d_out, int out_size, void* d_ws, size_t ws_size,
                              hipStream_t stream)
{
    const int*   idx        = (const int*)  d_in[0];
    const float* eps        = (const float*)d_in[1];
    const float* h0         = (const float*)d_in[2];
    const float* c0         = (const float*)d_in[3];
    const float* mean_table = (const float*)d_in[4];
    const float* var_table  = (const float*)d_in[5];
    const float* W_ih       = (const float*)d_in[6];
    const float* W_hh       = (const float*)d_in[7];
    const float* g_ih       = (const float*)d_in[8];
    const float* bln_ih     = (const float*)d_in[9];
    const float* g_hh       = (const float*)d_in[10];
    const float* bln_hh     = (const float*)d_in[11];
    const float* g_c        = (const float*)d_in[12];
    const float* bln_c      = (const float*)d_in[13];
    const float* W_out      = (const float*)d_in[14];
    const float* b_out      = (const float*)d_in[15];
    float* out = (float*)d_out;

    // ws layout (temporal aliasing keeps need at 61.44MB, under the proven 65.1MB):
    //  phase 1 (wstat/prep/lstm):  [0,19.66M)=repXf  [19.66,22.12M)=repS
    //  phase 2 (wsplit/gemm/red):  [0,3.07M)=Whi [3.07,6.14M)=Wlo [6.14,21.87M)=partial
    //  always: [22.12,61.44M)=hs bf16 ; [61.44M,+1088)=Scs
    char* wsb = (char*)d_ws;
    const size_t repXf_b = (size_t)LCH * B_SZ * 64;        // 19,660,800
    const size_t repS_b  = (size_t)LCH * B_SZ * 8;         //  2,457,600
    const size_t hs_b    = (size_t)B_SZ * KK * 2;          // 39,321,600
    const size_t w_b     = (size_t)NPAD * KK * 2;          //  3,072,000

    f16x8* repXf = (f16x8*)wsb;
    float2* repS = (float2*)(wsb + repXf_b);
    unsigned short* Whi = (unsigned short*)wsb;
    unsigned short* Wlo = (unsigned short*)(wsb + w_b);
    float* partial = (float*)(wsb + 2 * w_b);
    unsigned short* hs = (unsigned short*)(wsb + repXf_b + repS_b);
    float* Scs = (float*)(wsb + repXf_b + repS_b + hs_b);

    const size_t need = repXf_b + repS_b + hs_b + 272 * 4;
    if (ws_size < need) return;

    wstat_kernel<<<1, 256, 0, stream>>>(W_ih, Scs);
    prep_kernel<<<(B_SZ * LCH) / 256, 256, 0, stream>>>(idx, eps, mean_table, var_table,
                                                        Scs, repXf, repS);
    lstm_kernel<<<B_SZ / BB, 256, 0, stream>>>(h0, c0, W_ih, W_hh, g_ih, bln_ih,
                                               g_hh, bln_hh, g_c, bln_c,
                                               repXf, repS, hs);
    wsplit_kernel<<<(NPAD * KK / 8) / 256, 256, 0, stream>>>(W_out, Whi, Wlo);
    gemm_kernel<<<dim3(32, NSEG), 256, 0, stream>>>(hs, Whi, Wlo, partial);
    reduce_kernel<<<(B_SZ * LCH) / 256, 256, 0, stream>>>(partial, b_out, out);
}

// Round 7
// 486.784 us; speedup vs baseline: 2.5646x; 1.0208x over previous
//
#include <hip/hip_runtime.h>
#include <hip/hip_bf16.h>

#define LN_EPS 1e-5f
#define B_SZ 2048
#define LCH 150
#define HH 64
#define KK 9600
#define NSEG 12
#define KPS 800
#define NPAD 160
#define BB 8
#define RS 72
#define LSC 4096.0f
#define ISC (1.0f/4096.0f)

typedef __attribute__((ext_vector_type(8))) _Float16 f16x8;
typedef __attribute__((ext_vector_type(8))) short bf16x8;
typedef __attribute__((ext_vector_type(4))) float f32x4;

__device__ __forceinline__ float bf2f_lo(unsigned int u) { return __uint_as_float(u << 16); }
__device__ __forceinline__ float bf2f_hi(unsigned int u) { return __uint_as_float(u & 0xffff0000u); }
__device__ __forceinline__ unsigned short f2bf(float f) {
    unsigned int u = __float_as_uint(f);
    unsigned int r = (u + 0x7FFFu + ((u >> 16) & 1u)) >> 16;
    return (unsigned short)r;
}
__device__ __forceinline__ unsigned int cvtpk(float a, float b) {
    unsigned int r;
    asm("v_cvt_pk_bf16_f32 %0, %1, %2" : "=v"(r) : "v"(a), "v"(b));
    return r;
}
__device__ __forceinline__ float rcpf(float x) { return __builtin_amdgcn_rcpf(x); }
__device__ __forceinline__ float rsqf(float x) { return __builtin_amdgcn_rsqf(x); }

template<int CTRL>
__device__ __forceinline__ float dppadd16(float x) {
    int y = __builtin_amdgcn_update_dpp(0, __float_as_int(x), CTRL, 0xf, 0xf, true);
    return x + __int_as_float(y);
}
// sum within each 16-lane group (all lanes end with the sum)
__device__ __forceinline__ float red16(float x) {
    x = dppadd16<0xB1>(x);   // quad_perm 1,0,3,2
    x = dppadd16<0x4E>(x);   // quad_perm 2,3,0,1
    x = dppadd16<0x141>(x);  // row_half_mirror
    x = dppadd16<0x140>(x);  // row_mirror
    return x;
}

// -------- stats of W_ih: S = sum_n w_n w_n^T (16x16), cs = sum_n w_n --------
__global__ __launch_bounds__(256)
void wstat_kernel(const float* __restrict__ W_ih, float* __restrict__ Scs)
{
    const int tid = threadIdx.x;
    const int p = tid >> 4, q = tid & 15;
    float s = 0.f;
    for (int n = 0; n < 256; ++n)
        s += W_ih[n * 16 + p] * W_ih[n * 16 + q];
    Scs[p * 16 + q] = s;
    if (tid < 16) {
        float c = 0.f;
        for (int n = 0; n < 256; ++n) c += W_ih[n * 16 + tid];
        Scs[256 + tid] = c;
    }
}

// -------- prep: rep = eps*exp(0.5*logvar)+mu; fp16 limb A-frags + ih LN stats --------
__global__ __launch_bounds__(256)
void prep_kernel(const int* __restrict__ idx, const float* __restrict__ eps,
                 const float* __restrict__ mean_table, const float* __restrict__ var_table,
                 const float* __restrict__ Scs,
                 f16x8* __restrict__ repXf, float2* __restrict__ repS)
{
    const int gid = blockIdx.x * 256 + threadIdx.x;      // t*2048 + b
    const int t = gid >> 11, b = gid & 2047;
    const int id = idx[b * LCH + t];
    const float4* mp = (const float4*)(mean_table + (size_t)id * 16);
    const float4* vp = (const float4*)(var_table + (size_t)id * 16);
    const float4* ep = (const float4*)(eps + ((size_t)b * LCH + t) * 16);
    float x[16];
    #pragma unroll
    for (int q = 0; q < 4; ++q) {
        float4 m = mp[q], v = vp[q], e = ep[q];
        x[4*q+0] = e.x * __expf(0.5f * v.x) + m.x;
        x[4*q+1] = e.y * __expf(0.5f * v.y) + m.y;
        x[4*q+2] = e.z * __expf(0.5f * v.z) + m.z;
        x[4*q+3] = e.w * __expf(0.5f * v.w) + m.w;
    }
    float m1 = 0.f, qq = 0.f;
    #pragma unroll 4
    for (int p = 0; p < 16; ++p) {
        float sp = 0.f;
        #pragma unroll
        for (int q2 = 0; q2 < 16; ++q2) sp += Scs[p * 16 + q2] * x[q2];
        qq += x[p] * sp;
        m1 += Scs[256 + p] * x[p];
    }
    const float inv = 1.f / 256.f;
    m1 *= inv; qq *= inv;
    const float rs = rsqf(qq - m1 * m1 + LN_EPS);
    repS[gid] = make_float2(m1, rs);
    f16x8 H0, H1, L0, L1;
    #pragma unroll
    for (int f = 0; f < 8; ++f) {
        _Float16 h0_ = (_Float16)x[f];
        H0[f] = h0_; L0[f] = (_Float16)((x[f] - (float)h0_) * LSC);
        _Float16 h1_ = (_Float16)x[8 + f];
        H1[f] = h1_; L1[f] = (_Float16)((x[8 + f] - (float)h1_) * LSC);
    }
    f16x8* dst = repXf + (size_t)gid * 4;
    dst[0] = H0; dst[1] = H1; dst[2] = L0; dst[3] = L1;
}

// -------- 2-way bf16 split of W_out (rows 150..159 zero) --------
__global__ __launch_bounds__(256)
void wsplit_kernel(const float* __restrict__ W,
                   unsigned short* __restrict__ Whi, unsigned short* __restrict__ Wlo)
{
    const int gid = blockIdx.x * 256 + threadIdx.x;      // 160 * 1200
    const int row = gid / 1200;
    const int k8 = (gid - row * 1200) * 8;
    uint4 Hv = make_uint4(0, 0, 0, 0), Lv = Hv;
    if (row < 150) {
        const float* p = W + (size_t)row * KK + k8;
        unsigned int hu[4], lu[4];
        #pragma unroll
        for (int q = 0; q < 4; ++q) {
            float a = p[2 * q], b = p[2 * q + 1];
            unsigned int h = cvtpk(a, b);
            float da = a - bf2f_lo(h), db = b - bf2f_hi(h);
            hu[q] = h; lu[q] = cvtpk(da, db);
        }
        Hv = make_uint4(hu[0], hu[1], hu[2], hu[3]);
        Lv = make_uint4(lu[0], lu[1], lu[2], lu[3]);
    }
    *(uint4*)(Whi + (size_t)row * KK + k8) = Hv;
    *(uint4*)(Wlo + (size_t)row * KK + k8) = Lv;
}

// -------- MFMA LSTM: BB=8, A-rows 8-15 mirror rows 0-7 so both half-waves hold
// identical valid accumulators; scalar phase split BY ROW (no exchange):
// lo half-wave owns rows {row_blk+0,1}, hi half-wave rows {row_blk+2,3};
// each thread computes all 4 gates for its own 2 rows. --------
__global__ __launch_bounds__(256, 1)
void lstm_kernel(const float* __restrict__ h0, const float* __restrict__ c0,
                 const float* __restrict__ W_ih, const float* __restrict__ W_hh,
                 const float* __restrict__ g_ih, const float* __restrict__ bln_ih,
                 const float* __restrict__ g_hh, const float* __restrict__ bln_hh,
                 const float* __restrict__ g_c, const float* __restrict__ bln_c,
                 const f16x8* __restrict__ repXf, const float2* __restrict__ repS,
                 unsigned short* __restrict__ hs_out)
{
    const int tid = threadIdx.x;
    const int m = tid & 15;
    const int g = (tid >> 4) & 3;
    const int w = tid >> 6;
    const int row0 = blockIdx.x * BB;
    const int j = w * 16 + m;
    const bool lo = (tid & 63) < 32;     // half-wave id
    const int rb = lo ? 0 : 2;           // own r-pair base within the row-group
    const int row_blk = (g & 1) * 4;     // row block 0-3 vs 4-7

    __shared__ _Float16 hH[8 * RS];
    __shared__ _Float16 hL[8 * RS];
    __shared__ float2 st1[8][4];   // [row][w] : (sum, sumsq) of hh gates
    __shared__ float2 st2[8][4];   // [row][w] : (sum, sumsq) of c

    // ---- static weight fragments (all 4 tn: MFMA is wave-collective) ----
    f16x8 WHf[4][2], WLf[4][2], Bi1[4], Bi2[4];
    float gihc[4], ghhc[4], bsc[4];
    const bool g01 = (g < 2);
    #pragma unroll
    for (int tn = 0; tn < 4; ++tn) {
        const int n = tn * 64 + j;
        #pragma unroll
        for (int c = 0; c < 2; ++c) {
            const float* wp = W_hh + n * 64 + c * 32 + g * 8;
            #pragma unroll
            for (int q = 0; q < 8; ++q) {
                float v = wp[q];
                _Float16 h_ = (_Float16)v;
                WHf[tn][c][q] = h_;
                WLf[tn][c][q] = (_Float16)((v - (float)h_) * LSC);
            }
        }
        const float* ip = W_ih + n * 16 + (g & 1) * 8;
        #pragma unroll
        for (int q = 0; q < 8; ++q) {
            float v = ip[q];
            _Float16 h_ = (_Float16)v;
            _Float16 l_ = (_Float16)((v - (float)h_) * LSC);
            Bi1[tn][q] = g01 ? h_ : (_Float16)0.f;   // pass1: [WH | 0]
            Bi2[tn][q] = g01 ? l_ : h_;              // pass2: [WL'| WH]
        }
        gihc[tn] = g_ih[n];
        ghhc[tn] = g_hh[n];
        bsc[tn] = bln_ih[n] + bln_hh[n];
    }
    const float gcc = g_c[j], bcc = bln_c[j];

    // ---- state init: c for own 2 rows; h limbs in LDS (8 rows) ----
    float c_reg[2];
    c_reg[0] = c0[(size_t)(row0 + row_blk + rb + 0) * HH + j];
    c_reg[1] = c0[(size_t)(row0 + row_blk + rb + 1) * HH + j];
    #pragma unroll
    for (int it = 0; it < 2; ++it) {
        const int s = tid + it * 256;
        const int rr = s >> 6, jj = s & 63;
        float hv = h0[(size_t)(row0 + rr) * HH + jj];
        _Float16 Hh = (_Float16)hv;
        hH[rr * RS + jj] = Hh;
        hL[rr * RS + jj] = (_Float16)((hv - (float)Hh) * LSC);
    }

    // x / stats prefetch (t=0); MIRRORED row (m&7)
    const size_t rowx = (size_t)row0 + (m & 7);
    const int xoff = g;
    f16x8 AX = repXf[rowx * 4 + xoff];
    float4 mrsA = *(const float4*)&repS[row0 + row_blk];       // rows +0,+1
    float4 mrsB = *(const float4*)&repS[row0 + row_blk + 2];   // rows +2,+3
    __syncthreads();

    const float INV256 = 1.f / 256.f, INV64 = 1.f / 64.f;

    for (int t = 0; t < LCH; ++t) {
        // ---- A-frags (mirrored: lanes m and m+8 broadcast same row) ----
        const f16x8 AH0 = *(const f16x8*)&hH[(m & 7) * RS + g * 8];
        const f16x8 AH1 = *(const f16x8*)&hH[(m & 7) * RS + 32 + g * 8];
        const f16x8 AL0 = *(const f16x8*)&hL[(m & 7) * RS + g * 8];
        const f16x8 AL1 = *(const f16x8*)&hL[(m & 7) * RS + 32 + g * 8];

        f32x4 a1h[4], a2h[4], a1i[4], a2i[4];
        #pragma unroll
        for (int tn = 0; tn < 4; ++tn) {
            a1h[tn] = (f32x4)0.f; a2h[tn] = (f32x4)0.f;
            a1i[tn] = (f32x4)0.f; a2i[tn] = (f32x4)0.f;
        }
        #pragma unroll
        for (int tn = 0; tn < 4; ++tn) {
            a1h[tn] = __builtin_amdgcn_mfma_f32_16x16x32_f16(AH0, WHf[tn][0], a1h[tn], 0, 0, 0);
            a1h[tn] = __builtin_amdgcn_mfma_f32_16x16x32_f16(AH1, WHf[tn][1], a1h[tn], 0, 0, 0);
        }
        #pragma unroll
        for (int tn = 0; tn < 4; ++tn) {
            a2h[tn] = __builtin_amdgcn_mfma_f32_16x16x32_f16(AH0, WLf[tn][0], a2h[tn], 0, 0, 0);
            a2h[tn] = __builtin_amdgcn_mfma_f32_16x16x32_f16(AH1, WLf[tn][1], a2h[tn], 0, 0, 0);
            a2h[tn] = __builtin_amdgcn_mfma_f32_16x16x32_f16(AL0, WHf[tn][0], a2h[tn], 0, 0, 0);
            a2h[tn] = __builtin_amdgcn_mfma_f32_16x16x32_f16(AL1, WHf[tn][1], a2h[tn], 0, 0, 0);
        }
        #pragma unroll
        for (int tn = 0; tn < 4; ++tn) {
            a1i[tn] = __builtin_amdgcn_mfma_f32_16x16x32_f16(AX, Bi1[tn], a1i[tn], 0, 0, 0);
            a2i[tn] = __builtin_amdgcn_mfma_f32_16x16x32_f16(AX, Bi2[tn], a2i[tn], 0, 0, 0);
        }

        // ---- prefetch next step ----
        const int tp = (t + 1 < LCH) ? t + 1 : LCH - 1;
        const f16x8 AXn = repXf[((size_t)tp * 2048 + rowx) * 4 + xoff];
        const float4 mrsAn = *(const float4*)&repS[(size_t)tp * 2048 + row0 + row_blk];
        const float4 mrsBn = *(const float4*)&repS[(size_t)tp * 2048 + row0 + row_blk + 2];

        // ---- limb combine (identical numerics to round 5) ----
        float ahh[4][4], aih[4][4];
        #pragma unroll
        for (int tn = 0; tn < 4; ++tn)
            #pragma unroll
            for (int r = 0; r < 4; ++r) {
                ahh[tn][r] = fmaf(a2h[tn][r], ISC, a1h[tn][r]);
                aih[tn][r] = fmaf(a2i[tn][r], ISC, a1i[tn][r]);
            }

        // ---- LN-256 hh stats: each half computes its own 2 rows ----
        #pragma unroll
        for (int u = 0; u < 2; ++u) {
            const float a0 = lo ? ahh[0][u] : ahh[0][2 + u];
            const float a1 = lo ? ahh[1][u] : ahh[1][2 + u];
            const float a2 = lo ? ahh[2][u] : ahh[2][2 + u];
            const float a3 = lo ? ahh[3][u] : ahh[3][2 + u];
            float s = red16((a0 + a1) + (a2 + a3));
            float qv = red16(a0 * a0 + a1 * a1 + a2 * a2 + a3 * a3);
            if (m == 0) st1[row_blk + rb + u][w] = make_float2(s, qv);
        }
        __syncthreads();   // B1

        float mh_u[2], rsh_u[2];
        #pragma unroll
        for (int u = 0; u < 2; ++u) {
            const int row = row_blk + rb + u;
            float2 u0 = st1[row][0], u1 = st1[row][1];
            float2 u2 = st1[row][2], u3 = st1[row][3];
            float S = (u0.x + u1.x) + (u2.x + u3.x);
            float Q = (u0.y + u1.y) + (u2.y + u3.y);
            float mm = S * INV256;
            mh_u[u] = mm;
            rsh_u[u] = rsqf(Q * INV256 - mm * mm + LN_EPS);
        }
        const float mi_u[2]  = { lo ? mrsA.x : mrsB.x, lo ? mrsA.z : mrsB.z };
        const float rsi_u[2] = { lo ? mrsA.y : mrsB.y, lo ? mrsA.w : mrsB.w };

        // ---- all 4 gates for own 2 rows (8 exp-chains; tn compile-time) ----
        float act_[4][2];
        #pragma unroll
        for (int tn = 0; tn < 4; ++tn)
            #pragma unroll
            for (int u = 0; u < 2; ++u) {
                const float ah = lo ? ahh[tn][u] : ahh[tn][2 + u];
                const float ai = lo ? aih[tn][u] : aih[tn][2 + u];
                float gate = (ah - mh_u[u]) * rsh_u[u] * ghhc[tn]
                           + (ai - mi_u[u]) * rsi_u[u] * gihc[tn] + bsc[tn];
                if (tn == 2) act_[tn][u] = 2.f * rcpf(1.f + __expf(-2.f * gate)) - 1.f;
                else         act_[tn][u] = rcpf(1.f + __expf(-gate));
            }

        // ---- c update + LN-64 stats (own 2 rows) ----
        #pragma unroll
        for (int u = 0; u < 2; ++u) {
            c_reg[u] = fmaf(act_[1][u], c_reg[u], act_[0][u] * act_[2][u]);
            float sc = red16(c_reg[u]);
            float qc = red16(c_reg[u] * c_reg[u]);
            if (m == 0) st2[row_blk + rb + u][w] = make_float2(sc, qc);
        }
        __syncthreads();   // B2

        #pragma unroll
        for (int u = 0; u < 2; ++u) {
            const int row = row_blk + rb + u;
            float2 u0 = st2[row][0], u1 = st2[row][1];
            float2 u2 = st2[row][2], u3 = st2[row][3];
            float Sc = (u0.x + u1.x) + (u2.x + u3.x);
            float Qc = (u0.y + u1.y) + (u2.y + u3.y);
            float mc = Sc * INV64;
            float rsc = rsqf(Qc * INV64 - mc * mc + LN_EPS);
            float lnc = (c_reg[u] - mc) * rsc * gcc + bcc;
            float th = 2.f * rcpf(1.f + __expf(-2.f * lnc)) - 1.f;
            float h = act_[3][u] * th;
            _Float16 Hh = (_Float16)h;
            hH[row * RS + j] = Hh;
            hL[row * RS + j] = (_Float16)((h - (float)Hh) * LSC);
            hs_out[(size_t)(row0 + row) * KK + t * HH + j] = f2bf(h);
        }
        __syncthreads();   // B3

        AX = AXn; mrsA = mrsAn; mrsB = mrsBn;
    }
}

// -------- MFMA output GEMM (round-5 proven): 64-row blocks, K-split partials --------
__global__ __launch_bounds__(256)
void gemm_kernel(const unsigned short* __restrict__ hs,
                 const unsigned short* __restrict__ Whi,
                 const unsigned short* __restrict__ Wlo,
                 float* __restrict__ partial)
{
    const int mb = blockIdx.x;       // 0..31
    const int seg = blockIdx.y;      // 0..NSEG-1
    const int tid = threadIdx.x;
    const int l = tid & 63;
    const int w = tid >> 6;
    const int lane16 = l & 15;
    const int lgrp = l >> 4;

    f32x4 acc[10];
    #pragma unroll
    for (int nt = 0; nt < 10; ++nt) acc[nt] = (f32x4)0.f;

    const int kstart = seg * KPS + lgrp * 8;
    const unsigned short* ap = hs + (size_t)(mb * 64 + w * 16 + lane16) * KK + kstart;

    for (int s = 0; s < KPS / 32; ++s) {
        const int k = s * 32;
        union { bf16x8 v; uint4 u; } A;
        A.u = *(const uint4*)(ap + k);
        #pragma unroll
        for (int nt = 0; nt < 10; ++nt) {
            const size_t boff = (size_t)(nt * 16 + lane16) * KK + kstart + k;
            union { bf16x8 v; uint4 u; } Bh, Bl;
            Bh.u = *(const uint4*)(Whi + boff);
            Bl.u = *(const uint4*)(Wlo + boff);
            acc[nt] = __builtin_amdgcn_mfma_f32_16x16x32_bf16(A.v, Bh.v, acc[nt], 0, 0, 0);
            acc[nt] = __builtin_amdgcn_mfma_f32_16x16x32_bf16(A.v, Bl.v, acc[nt], 0, 0, 0);
        }
    }
    float* po = partial + ((size_t)seg * B_SZ + mb * 64 + w * 16 + lgrp * 4) * NPAD + lane16;
    #pragma unroll
    for (int nt = 0; nt < 10; ++nt)
        #pragma unroll
        for (int r = 0; r < 4; ++r)
            po[(size_t)r * NPAD + nt * 16] = acc[nt][r];
}

__global__ __launch_bounds__(256)
void reduce_kernel(const float* __restrict__ partial, const float* __restrict__ b_out,
                   float* __restrict__ out)
{
    const int i = blockIdx.x * 256 + threadIdx.x;   // row*150 + c
    const int row = i / 150;
    const int c = i - row * 150;
    float s = 0.f;
    #pragma unroll
    for (int g = 0; g < NSEG; ++g)
        s += partial[((size_t)g * B_SZ + row) * NPAD + c];
    out[i] = s + b_out[c];
}

extern "C" void kernel_launch(void* const* d_in, const int* in_sizes, int n_in,
                              void* d_out, int out_size, void* d_ws, size_t ws_size,
                              hipStream_t stream)
{
    const int*   idx        = (const int*)  d_in[0];
    const float* eps        = (const float*)d_in[1];
    const float* h0         = (const float*)d_in[2];
    const float* c0         = (const float*)d_in[3];
    const float* mean_table = (const float*)d_in[4];
    const float* var_table  = (const float*)d_in[5];
    const float* W_ih       = (const float*)d_in[6];
    const float* W_hh       = (const float*)d_in[7];
    const float* g_ih       = (const float*)d_in[8];
    const float* bln_ih     = (const float*)d_in[9];
    const float* g_hh       = (const float*)d_in[10];
    const float* bln_hh     = (const float*)d_in[11];
    const float* g_c        = (const float*)d_in[12];
    const float* bln_c      = (const float*)d_in[13];
    const float* W_out      = (const float*)d_in[14];
    const float* b_out      = (const float*)d_in[15];
    float* out = (float*)d_out;

    // ws layout (temporal aliasing):
    //  phase 1 (wstat/prep/lstm):  [0,19.66M)=repXf  [19.66,22.12M)=repS
    //  phase 2 (wsplit/gemm/red):  [0,3.07M)=Whi [3.07,6.14M)=Wlo [6.14,21.87M)=partial
    //  always: [22.12,61.44M)=hs bf16 ; [61.44M,+1088B)=Scs
    char* wsb = (char*)d_ws;
    const size_t repXf_b = (size_t)LCH * B_SZ * 64;        // 19,660,800
    const size_t repS_b  = (size_t)LCH * B_SZ * 8;         //  2,457,600
    const size_t hs_b    = (size_t)B_SZ * KK * 2;          // 39,321,600
    const size_t w_b     = (size_t)NPAD * KK * 2;          //  3,072,000

    f16x8* repXf = (f16x8*)wsb;
    float2* repS = (float2*)(wsb + repXf_b);
    unsigned short* Whi = (unsigned short*)wsb;
    unsigned short* Wlo = (unsigned short*)(wsb + w_b);
    float* partial = (float*)(wsb + 2 * w_b);
    unsigned short* hs = (unsigned short*)(wsb + repXf_b + repS_b);
    float* Scs = (float*)(wsb + repXf_b + repS_b + hs_b);

    const size_t need = repXf_b + repS_b + hs_b + 272 * 4;
    if (ws_size < need) return;

    wstat_kernel<<<1, 256, 0, stream>>>(W_ih, Scs);
    prep_kernel<<<(B_SZ * LCH) / 256, 256, 0, stream>>>(idx, eps, mean_table, var_table,
                                                        Scs, repXf, repS);
    lstm_kernel<<<B_SZ / BB, 256, 0, stream>>>(h0, c0, W_ih, W_hh, g_ih, bln_ih,
                                               g_hh, bln_hh, g_c, bln_c,
                                               repXf, repS, hs);
    wsplit_kernel<<<(NPAD * KK / 8) / 256, 256, 0, stream>>>(W_out, Whi, Wlo);
    gemm_kernel<<<dim3(32, NSEG), 256, 0, stream>>>(hs, Whi, Wlo, partial);
    reduce_kernel<<<(B_SZ * LCH) / 256, 256, 0, stream>>>(partial, b_out, out);
}

// Round 8
// 384.850 us; speedup vs baseline: 3.2439x; 1.2649x over previous
//
#include <hip/hip_runtime.h>
#include <hip/hip_bf16.h>

#define LN_EPS 1e-5f
#define B_SZ 2048
#define LCH 150
#define HH 64
#define KK 9600
#define NSEG 12
#define KPS 800
#define NPAD 160
#define BB 8
#define RS 72
#define LSC 4096.0f
#define ISC (1.0f/4096.0f)

typedef __attribute__((ext_vector_type(8))) _Float16 f16x8;
typedef __attribute__((ext_vector_type(8))) short bf16x8;
typedef __attribute__((ext_vector_type(4))) float f32x4;

__device__ __forceinline__ float bf2f_lo(unsigned int u) { return __uint_as_float(u << 16); }
__device__ __forceinline__ float bf2f_hi(unsigned int u) { return __uint_as_float(u & 0xffff0000u); }
__device__ __forceinline__ unsigned short f2bf(float f) {
    unsigned int u = __float_as_uint(f);
    unsigned int r = (u + 0x7FFFu + ((u >> 16) & 1u)) >> 16;
    return (unsigned short)r;
}
__device__ __forceinline__ unsigned int cvtpk(float a, float b) {
    unsigned int r;
    asm("v_cvt_pk_bf16_f32 %0, %1, %2" : "=v"(r) : "v"(a), "v"(b));
    return r;
}
__device__ __forceinline__ float rcpf(float x) { return __builtin_amdgcn_rcpf(x); }
__device__ __forceinline__ float rsqf(float x) { return __builtin_amdgcn_rsqf(x); }

template<int CTRL>
__device__ __forceinline__ float dppadd16(float x) {
    int y = __builtin_amdgcn_update_dpp(0, __float_as_int(x), CTRL, 0xf, 0xf, true);
    return x + __int_as_float(y);
}
// sum within each 16-lane group (all lanes end with the sum)
__device__ __forceinline__ float red16(float x) {
    x = dppadd16<0xB1>(x);   // quad_perm 1,0,3,2
    x = dppadd16<0x4E>(x);   // quad_perm 2,3,0,1
    x = dppadd16<0x141>(x);  // row_half_mirror
    x = dppadd16<0x140>(x);  // row_mirror
    return x;
}

// -------- stats of W_ih: S = sum_n w_n w_n^T (16x16), cs = sum_n w_n --------
__global__ __launch_bounds__(256)
void wstat_kernel(const float* __restrict__ W_ih, float* __restrict__ Scs)
{
    const int tid = threadIdx.x;
    const int p = tid >> 4, q = tid & 15;
    float s = 0.f;
    for (int n = 0; n < 256; ++n)
        s += W_ih[n * 16 + p] * W_ih[n * 16 + q];
    Scs[p * 16 + q] = s;
    if (tid < 16) {
        float c = 0.f;
        for (int n = 0; n < 256; ++n) c += W_ih[n * 16 + tid];
        Scs[256 + tid] = c;
    }
}

// -------- prep: rep = eps*exp(0.5*logvar)+mu; fp16 limb A-frags + ih LN stats --------
__global__ __launch_bounds__(256)
void prep_kernel(const int* __restrict__ idx, const float* __restrict__ eps,
                 const float* __restrict__ mean_table, const float* __restrict__ var_table,
                 const float* __restrict__ Scs,
                 f16x8* __restrict__ repXf, float2* __restrict__ repS)
{
    const int gid = blockIdx.x * 256 + threadIdx.x;      // t*2048 + b
    const int t = gid >> 11, b = gid & 2047;
    const int id = idx[b * LCH + t];
    const float4* mp = (const float4*)(mean_table + (size_t)id * 16);
    const float4* vp = (const float4*)(var_table + (size_t)id * 16);
    const float4* ep = (const float4*)(eps + ((size_t)b * LCH + t) * 16);
    float x[16];
    #pragma unroll
    for (int q = 0; q < 4; ++q) {
        float4 m = mp[q], v = vp[q], e = ep[q];
        x[4*q+0] = e.x * __expf(0.5f * v.x) + m.x;
        x[4*q+1] = e.y * __expf(0.5f * v.y) + m.y;
        x[4*q+2] = e.z * __expf(0.5f * v.z) + m.z;
        x[4*q+3] = e.w * __expf(0.5f * v.w) + m.w;
    }
    float m1 = 0.f, qq = 0.f;
    #pragma unroll 4
    for (int p = 0; p < 16; ++p) {
        float sp = 0.f;
        #pragma unroll
        for (int q2 = 0; q2 < 16; ++q2) sp += Scs[p * 16 + q2] * x[q2];
        qq += x[p] * sp;
        m1 += Scs[256 + p] * x[p];
    }
    const float inv = 1.f / 256.f;
    m1 *= inv; qq *= inv;
    const float rs = rsqf(qq - m1 * m1 + LN_EPS);
    repS[gid] = make_float2(m1, rs);
    f16x8 H0, H1, L0, L1;
    #pragma unroll
    for (int f = 0; f < 8; ++f) {
        _Float16 h0_ = (_Float16)x[f];
        H0[f] = h0_; L0[f] = (_Float16)((x[f] - (float)h0_) * LSC);
        _Float16 h1_ = (_Float16)x[8 + f];
        H1[f] = h1_; L1[f] = (_Float16)((x[8 + f] - (float)h1_) * LSC);
    }
    f16x8* dst = repXf + (size_t)gid * 4;
    dst[0] = H0; dst[1] = H1; dst[2] = L0; dst[3] = L1;
}

// -------- 2-way bf16 split of W_out (rows 150..159 zero) --------
__global__ __launch_bounds__(256)
void wsplit_kernel(const float* __restrict__ W,
                   unsigned short* __restrict__ Whi, unsigned short* __restrict__ Wlo)
{
    const int gid = blockIdx.x * 256 + threadIdx.x;      // 160 * 1200
    const int row = gid / 1200;
    const int k8 = (gid - row * 1200) * 8;
    uint4 Hv = make_uint4(0, 0, 0, 0), Lv = Hv;
    if (row < 150) {
        const float* p = W + (size_t)row * KK + k8;
        unsigned int hu[4], lu[4];
        #pragma unroll
        for (int q = 0; q < 4; ++q) {
            float a = p[2 * q], b = p[2 * q + 1];
            unsigned int h = cvtpk(a, b);
            float da = a - bf2f_lo(h), db = b - bf2f_hi(h);
            hu[q] = h; lu[q] = cvtpk(da, db);
        }
        Hv = make_uint4(hu[0], hu[1], hu[2], hu[3]);
        Lv = make_uint4(lu[0], lu[1], lu[2], lu[3]);
    }
    *(uint4*)(Whi + (size_t)row * KK + k8) = Hv;
    *(uint4*)(Wlo + (size_t)row * KK + k8) = Lv;
}

// -------- MFMA LSTM: BB=8, A-rows 8-15 mirror rows 0-7; scalar phase split BY ROW.
// All per-thread arrays are strictly compile-time indexed; cross-half selection is
// done with value-level ternaries on NAMED SCALARS only (prevents the round-7
// promote-alloca-to-LDS regression: LDS 19456B / 71M bank conflicts). --------
__global__ __launch_bounds__(256, 1)
void lstm_kernel(const float* __restrict__ h0, const float* __restrict__ c0,
                 const float* __restrict__ W_ih, const float* __restrict__ W_hh,
                 const float* __restrict__ g_ih, const float* __restrict__ bln_ih,
                 const float* __restrict__ g_hh, const float* __restrict__ bln_hh,
                 const float* __restrict__ g_c, const float* __restrict__ bln_c,
                 const f16x8* __restrict__ repXf, const float2* __restrict__ repS,
                 unsigned short* __restrict__ hs_out)
{
    const int tid = threadIdx.x;
    const int m = tid & 15;
    const int g = (tid >> 4) & 3;
    const int w = tid >> 6;
    const int row0 = blockIdx.x * BB;
    const int j = w * 16 + m;
    const bool lo = (tid & 63) < 32;     // half-wave id
    const int rb = lo ? 0 : 2;           // own r-pair base within the row-group
    const int row_blk = (g & 1) * 4;     // row block 0-3 vs 4-7

    __shared__ _Float16 hH[8 * RS];
    __shared__ _Float16 hL[8 * RS];
    __shared__ float2 st1[8][4];   // [row][w] : (sum, sumsq) of hh gates
    __shared__ float2 st2[8][4];   // [row][w] : (sum, sumsq) of c

    // ---- static weight fragments (all 4 tn: MFMA is wave-collective) ----
    f16x8 WHf[4][2], WLf[4][2], Bi1[4], Bi2[4];
    float gihc[4], ghhc[4], bsc[4];
    const bool g01 = (g < 2);
    #pragma unroll
    for (int tn = 0; tn < 4; ++tn) {
        const int n = tn * 64 + j;
        #pragma unroll
        for (int c = 0; c < 2; ++c) {
            const float* wp = W_hh + n * 64 + c * 32 + g * 8;
            #pragma unroll
            for (int q = 0; q < 8; ++q) {
                float v = wp[q];
                _Float16 h_ = (_Float16)v;
                WHf[tn][c][q] = h_;
                WLf[tn][c][q] = (_Float16)((v - (float)h_) * LSC);
            }
        }
        const float* ip = W_ih + n * 16 + (g & 1) * 8;
        #pragma unroll
        for (int q = 0; q < 8; ++q) {
            float v = ip[q];
            _Float16 h_ = (_Float16)v;
            _Float16 l_ = (_Float16)((v - (float)h_) * LSC);
            Bi1[tn][q] = g01 ? h_ : (_Float16)0.f;   // pass1: [WH | 0]
            Bi2[tn][q] = g01 ? l_ : h_;              // pass2: [WL'| WH]
        }
        gihc[tn] = g_ih[n];
        ghhc[tn] = g_hh[n];
        bsc[tn] = bln_ih[n] + bln_hh[n];
    }
    const float gcc = g_c[j], bcc = bln_c[j];

    // ---- state init: c for own 2 rows; h limbs in LDS (8 rows) ----
    float c_reg[2];
    c_reg[0] = c0[(size_t)(row0 + row_blk + rb + 0) * HH + j];
    c_reg[1] = c0[(size_t)(row0 + row_blk + rb + 1) * HH + j];
    #pragma unroll
    for (int it = 0; it < 2; ++it) {
        const int s = tid + it * 256;
        const int rr = s >> 6, jj = s & 63;
        float hv = h0[(size_t)(row0 + rr) * HH + jj];
        _Float16 Hh = (_Float16)hv;
        hH[rr * RS + jj] = Hh;
        hL[rr * RS + jj] = (_Float16)((hv - (float)Hh) * LSC);
    }

    // x / stats prefetch (t=0); MIRRORED row (m&7)
    const size_t rowx = (size_t)row0 + (m & 7);
    const int xoff = g;
    f16x8 AX = repXf[rowx * 4 + xoff];
    float4 mrsA = *(const float4*)&repS[row0 + row_blk];       // rows +0,+1
    float4 mrsB = *(const float4*)&repS[row0 + row_blk + 2];   // rows +2,+3
    __syncthreads();

    const float INV256 = 1.f / 256.f, INV64 = 1.f / 64.f;

    for (int t = 0; t < LCH; ++t) {
        // ---- A-frags (mirrored: lanes m and m+8 broadcast same row) ----
        const f16x8 AH0 = *(const f16x8*)&hH[(m & 7) * RS + g * 8];
        const f16x8 AH1 = *(const f16x8*)&hH[(m & 7) * RS + 32 + g * 8];
        const f16x8 AL0 = *(const f16x8*)&hL[(m & 7) * RS + g * 8];
        const f16x8 AL1 = *(const f16x8*)&hL[(m & 7) * RS + 32 + g * 8];

        f32x4 a1h[4], a2h[4], a1i[4], a2i[4];
        #pragma unroll
        for (int tn = 0; tn < 4; ++tn) {
            a1h[tn] = (f32x4)0.f; a2h[tn] = (f32x4)0.f;
            a1i[tn] = (f32x4)0.f; a2i[tn] = (f32x4)0.f;
        }
        #pragma unroll
        for (int tn = 0; tn < 4; ++tn) {
            a1h[tn] = __builtin_amdgcn_mfma_f32_16x16x32_f16(AH0, WHf[tn][0], a1h[tn], 0, 0, 0);
            a1h[tn] = __builtin_amdgcn_mfma_f32_16x16x32_f16(AH1, WHf[tn][1], a1h[tn], 0, 0, 0);
        }
        #pragma unroll
        for (int tn = 0; tn < 4; ++tn) {
            a2h[tn] = __builtin_amdgcn_mfma_f32_16x16x32_f16(AH0, WLf[tn][0], a2h[tn], 0, 0, 0);
            a2h[tn] = __builtin_amdgcn_mfma_f32_16x16x32_f16(AH1, WLf[tn][1], a2h[tn], 0, 0, 0);
            a2h[tn] = __builtin_amdgcn_mfma_f32_16x16x32_f16(AL0, WHf[tn][0], a2h[tn], 0, 0, 0);
            a2h[tn] = __builtin_amdgcn_mfma_f32_16x16x32_f16(AL1, WHf[tn][1], a2h[tn], 0, 0, 0);
        }
        #pragma unroll
        for (int tn = 0; tn < 4; ++tn) {
            a1i[tn] = __builtin_amdgcn_mfma_f32_16x16x32_f16(AX, Bi1[tn], a1i[tn], 0, 0, 0);
            a2i[tn] = __builtin_amdgcn_mfma_f32_16x16x32_f16(AX, Bi2[tn], a2i[tn], 0, 0, 0);
        }

        // ---- prefetch next step ----
        const int tp = (t + 1 < LCH) ? t + 1 : LCH - 1;
        const f16x8 AXn = repXf[((size_t)tp * 2048 + rowx) * 4 + xoff];
        const float4 mrsAn = *(const float4*)&repS[(size_t)tp * 2048 + row0 + row_blk];
        const float4 mrsBn = *(const float4*)&repS[(size_t)tp * 2048 + row0 + row_blk + 2];

        // ---- limb combine for OWN rows only; value-level selects on named
        //      scalars, constant indices everywhere (numerics == round 5) ----
        float ohh[4][2], oih[4][2];
        #pragma unroll
        for (int tn = 0; tn < 4; ++tn) {
            const float p0 = a1h[tn][0], p1 = a1h[tn][1], p2 = a1h[tn][2], p3 = a1h[tn][3];
            const float q0 = a2h[tn][0], q1 = a2h[tn][1], q2 = a2h[tn][2], q3 = a2h[tn][3];
            ohh[tn][0] = fmaf(lo ? q0 : q2, ISC, lo ? p0 : p2);
            ohh[tn][1] = fmaf(lo ? q1 : q3, ISC, lo ? p1 : p3);
            const float r0 = a1i[tn][0], r1 = a1i[tn][1], r2 = a1i[tn][2], r3 = a1i[tn][3];
            const float s0 = a2i[tn][0], s1 = a2i[tn][1], s2 = a2i[tn][2], s3 = a2i[tn][3];
            oih[tn][0] = fmaf(lo ? s0 : s2, ISC, lo ? r0 : r2);
            oih[tn][1] = fmaf(lo ? s1 : s3, ISC, lo ? r1 : r3);
        }

        // ---- LN-256 hh stats: each half computes its own 2 rows ----
        #pragma unroll
        for (int u = 0; u < 2; ++u) {
            const float a0 = ohh[0][u], a1 = ohh[1][u], a2 = ohh[2][u], a3 = ohh[3][u];
            float s = red16((a0 + a1) + (a2 + a3));
            float qv = red16(a0 * a0 + a1 * a1 + a2 * a2 + a3 * a3);
            if (m == 0) st1[row_blk + rb + u][w] = make_float2(s, qv);
        }
        __syncthreads();   // B1

        float mh_u[2], rsh_u[2];
        #pragma unroll
        for (int u = 0; u < 2; ++u) {
            const int row = row_blk + rb + u;
            float2 u0 = st1[row][0], u1 = st1[row][1];
            float2 u2 = st1[row][2], u3 = st1[row][3];
            float S = (u0.x + u1.x) + (u2.x + u3.x);
            float Q = (u0.y + u1.y) + (u2.y + u3.y);
            float mm = S * INV256;
            mh_u[u] = mm;
            rsh_u[u] = rsqf(Q * INV256 - mm * mm + LN_EPS);
        }
        const float mi0  = lo ? mrsA.x : mrsB.x;
        const float mi1  = lo ? mrsA.z : mrsB.z;
        const float rsi0 = lo ? mrsA.y : mrsB.y;
        const float rsi1 = lo ? mrsA.w : mrsB.w;

        // ---- all 4 gates for own 2 rows (8 exp-chains; tn compile-time) ----
        float act_[4][2];
        #pragma unroll
        for (int tn = 0; tn < 4; ++tn) {
            {
                float gate = (ohh[tn][0] - mh_u[0]) * rsh_u[0] * ghhc[tn]
                           + (oih[tn][0] - mi0) * rsi0 * gihc[tn] + bsc[tn];
                if (tn == 2) act_[tn][0] = 2.f * rcpf(1.f + __expf(-2.f * gate)) - 1.f;
                else         act_[tn][0] = rcpf(1.f + __expf(-gate));
            }
            {
                float gate = (ohh[tn][1] - mh_u[1]) * rsh_u[1] * ghhc[tn]
                           + (oih[tn][1] - mi1) * rsi1 * gihc[tn] + bsc[tn];
                if (tn == 2) act_[tn][1] = 2.f * rcpf(1.f + __expf(-2.f * gate)) - 1.f;
                else         act_[tn][1] = rcpf(1.f + __expf(-gate));
            }
        }

        // ---- c update + LN-64 stats (own 2 rows) ----
        #pragma unroll
        for (int u = 0; u < 2; ++u) {
            c_reg[u] = fmaf(act_[1][u], c_reg[u], act_[0][u] * act_[2][u]);
            float sc = red16(c_reg[u]);
            float qc = red16(c_reg[u] * c_reg[u]);
            if (m == 0) st2[row_blk + rb + u][w] = make_float2(sc, qc);
        }
        __syncthreads();   // B2

        #pragma unroll
        for (int u = 0; u < 2; ++u) {
            const int row = row_blk + rb + u;
            float2 u0 = st2[row][0], u1 = st2[row][1];
            float2 u2 = st2[row][2], u3 = st2[row][3];
            float Sc = (u0.x + u1.x) + (u2.x + u3.x);
            float Qc = (u0.y + u1.y) + (u2.y + u3.y);
            float mc = Sc * INV64;
            float rsc = rsqf(Qc * INV64 - mc * mc + LN_EPS);
            float lnc = (c_reg[u] - mc) * rsc * gcc + bcc;
            float th = 2.f * rcpf(1.f + __expf(-2.f * lnc)) - 1.f;
            float h = act_[3][u] * th;
            _Float16 Hh = (_Float16)h;
            hH[row * RS + j] = Hh;
            hL[row * RS + j] = (_Float16)((h - (float)Hh) * LSC);
            hs_out[(size_t)(row0 + row) * KK + t * HH + j] = f2bf(h);
        }
        __syncthreads();   // B3

        AX = AXn; mrsA = mrsAn; mrsB = mrsBn;
    }
}

// -------- MFMA output GEMM (round-5 proven): 64-row blocks, K-split partials --------
__global__ __launch_bounds__(256)
void gemm_kernel(const unsigned short* __restrict__ hs,
                 const unsigned short* __restrict__ Whi,
                 const unsigned short* __restrict__ Wlo,
                 float* __restrict__ partial)
{
    const int mb = blockIdx.x;       // 0..31
    const int seg = blockIdx.y;      // 0..NSEG-1
    const int tid = threadIdx.x;
    const int l = tid & 63;
    const int w = tid >> 6;
    const int lane16 = l & 15;
    const int lgrp = l >> 4;

    f32x4 acc[10];
    #pragma unroll
    for (int nt = 0; nt < 10; ++nt) acc[nt] = (f32x4)0.f;

    const int kstart = seg * KPS + lgrp * 8;
    const unsigned short* ap = hs + (size_t)(mb * 64 + w * 16 + lane16) * KK + kstart;

    for (int s = 0; s < KPS / 32; ++s) {
        const int k = s * 32;
        union { bf16x8 v; uint4 u; } A;
        A.u = *(const uint4*)(ap + k);
        #pragma unroll
        for (int nt = 0; nt < 10; ++nt) {
            const size_t boff = (size_t)(nt * 16 + lane16) * KK + kstart + k;
            union { bf16x8 v; uint4 u; } Bh, Bl;
            Bh.u = *(const uint4*)(Whi + boff);
            Bl.u = *(const uint4*)(Wlo + boff);
            acc[nt] = __builtin_amdgcn_mfma_f32_16x16x32_bf16(A.v, Bh.v, acc[nt], 0, 0, 0);
            acc[nt] = __builtin_amdgcn_mfma_f32_16x16x32_bf16(A.v, Bl.v, acc[nt], 0, 0, 0);
        }
    }
    float* po = partial + ((size_t)seg * B_SZ + mb * 64 + w * 16 + lgrp * 4) * NPAD + lane16;
    #pragma unroll
    for (int nt = 0; nt < 10; ++nt)
        #pragma unroll
        for (int r = 0; r < 4; ++r)
            po[(size_t)r * NPAD + nt * 16] = acc[nt][r];
}

__global__ __launch_bounds__(256)
void reduce_kernel(const float* __restrict__ partial, const float* __restrict__ b_out,
                   float* __restrict__ out)
{
    const int i = blockIdx.x * 256 + threadIdx.x;   // row*150 + c
    const int row = i / 150;
    const int c = i - row * 150;
    float s = 0.f;
    #pragma unroll
    for (int g = 0; g < NSEG; ++g)
        s += partial[((size_t)g * B_SZ + row) * NPAD + c];
    out[i] = s + b_out[c];
}

extern "C" void kernel_launch(void* const* d_in, const int* in_sizes, int n_in,
                              void* d_out, int out_size, void* d_ws, size_t ws_size,
                              hipStream_t stream)
{
    const int*   idx        = (const int*)  d_in[0];
    const float* eps        = (const float*)d_in[1];
    const float* h0         = (const float*)d_in[2];
    const float* c0         = (const float*)d_in[3];
    const float* mean_table = (const float*)d_in[4];
    const float* var_table  = (const float*)d_in[5];
    const float* W_ih       = (const float*)d_in[6];
    const float* W_hh       = (const float*)d_in[7];
    const float* g_ih       = (const float*)d_in[8];
    const float* bln_ih     = (const float*)d_in[9];
    const float* g_hh       = (const float*)d_in[10];
    const float* bln_hh     = (const float*)d_in[11];
    const float* g_c        = (const float*)d_in[12];
    const float* bln_c      = (const float*)d_in[13];
    const float* W_out      = (const float*)d_in[14];
    const float* b_out      = (const float*)d_in[15];
    float* out = (float*)d_out;

    // ws layout (temporal aliasing):
    //  phase 1 (wstat/prep/lstm):  [0,19.66M)=repXf  [19.66,22.12M)=repS
    //  phase 2 (wsplit/gemm/red):  [0,3.07M)=Whi [3.07,6.14M)=Wlo [6.14,21.87M)=partial
    //  always: [22.12,61.44M)=hs bf16 ; [61.44M,+1088B)=Scs
    char* wsb = (char*)d_ws;
    const size_t repXf_b = (size_t)LCH * B_SZ * 64;        // 19,660,800
    const size_t repS_b  = (size_t)LCH * B_SZ * 8;         //  2,457,600
    const size_t hs_b    = (size_t)B_SZ * KK * 2;          // 39,321,600
    const size_t w_b     = (size_t)NPAD * KK * 2;          //  3,072,000

    f16x8* repXf = (f16x8*)wsb;
    float2* repS = (float2*)(wsb + repXf_b);
    unsigned short* Whi = (unsigned short*)wsb;
    unsigned short* Wlo = (unsigned short*)(wsb + w_b);
    float* partial = (float*)(wsb + 2 * w_b);
    unsigned short* hs = (unsigned short*)(wsb + repXf_b + repS_b);
    float* Scs = (float*)(wsb + repXf_b + repS_b + hs_b);

    const size_t need = repXf_b + repS_b + hs_b + 272 * 4;
    if (ws_size < need) return;

    wstat_kernel<<<1, 256, 0, stream>>>(W_ih, Scs);
    prep_kernel<<<(B_SZ * LCH) / 256, 256, 0, stream>>>(idx, eps, mean_table, var_table,
                                                        Scs, repXf, repS);
    lstm_kernel<<<B_SZ / BB, 256, 0, stream>>>(h0, c0, W_ih, W_hh, g_ih, bln_ih,
                                               g_hh, bln_hh, g_c, bln_c,
                                               repXf, repS, hs);
    wsplit_kernel<<<(NPAD * KK / 8) / 256, 256, 0, stream>>>(W_out, Whi, Wlo);
    gemm_kernel<<<dim3(32, NSEG), 256, 0, stream>>>(hs, Whi, Wlo, partial);
    reduce_kernel<<<(B_SZ * LCH) / 256, 256, 0, stream>>>(partial, b_out, out);
}

// Round 9
// 267.142 us; speedup vs baseline: 4.6733x; 1.4406x over previous
//
#include <hip/hip_runtime.h>
#include <hip/hip_bf16.h>

#define LN_EPS 1e-5f
#define B_SZ 2048
#define LCH 150
#define HH 64
#define KK 9600
#define NSEG 16
#define NPAD 160
#define BB 4
#define RS 72
#define LSC 4096.0f
#define ISC (1.0f/4096.0f)

typedef __attribute__((ext_vector_type(8))) _Float16 f16x8;
typedef __attribute__((ext_vector_type(4))) float f32x4;

__device__ __forceinline__ float rcpf(float x) { return __builtin_amdgcn_rcpf(x); }
__device__ __forceinline__ float rsqf(float x) { return __builtin_amdgcn_rsqf(x); }

template<int CTRL>
__device__ __forceinline__ float dppadd16(float x) {
    int y = __builtin_amdgcn_update_dpp(0, __float_as_int(x), CTRL, 0xf, 0xf, true);
    return x + __int_as_float(y);
}
// sum within each 16-lane group (all lanes end with the sum)
__device__ __forceinline__ float red16(float x) {
    x = dppadd16<0xB1>(x);   // quad_perm 1,0,3,2
    x = dppadd16<0x4E>(x);   // quad_perm 2,3,0,1
    x = dppadd16<0x141>(x);  // row_half_mirror
    x = dppadd16<0x140>(x);  // row_mirror
    return x;
}

// -------- stats of W_ih: S = sum_n w_n w_n^T (16x16), cs = sum_n w_n --------
__global__ __launch_bounds__(256)
void wstat_kernel(const float* __restrict__ W_ih, float* __restrict__ Scs)
{
    const int tid = threadIdx.x;
    const int p = tid >> 4, q = tid & 15;
    float s = 0.f;
    for (int n = 0; n < 256; ++n)
        s += W_ih[n * 16 + p] * W_ih[n * 16 + q];
    Scs[p * 16 + q] = s;
    if (tid < 16) {
        float c = 0.f;
        for (int n = 0; n < 256; ++n) c += W_ih[n * 16 + tid];
        Scs[256 + tid] = c;
    }
}

// -------- prep: rep = eps*exp(0.5*logvar)+mu; fp16 limb A-frags + ih LN stats --------
__global__ __launch_bounds__(256)
void prep_kernel(const int* __restrict__ idx, const float* __restrict__ eps,
                 const float* __restrict__ mean_table, const float* __restrict__ var_table,
                 const float* __restrict__ Scs,
                 f16x8* __restrict__ repXf, float2* __restrict__ repS)
{
    const int gid = blockIdx.x * 256 + threadIdx.x;      // t*2048 + b
    const int t = gid >> 11, b = gid & 2047;
    const int id = idx[b * LCH + t];
    const float4* mp = (const float4*)(mean_table + (size_t)id * 16);
    const float4* vp = (const float4*)(var_table + (size_t)id * 16);
    const float4* ep = (const float4*)(eps + ((size_t)b * LCH + t) * 16);
    float x[16];
    #pragma unroll
    for (int q = 0; q < 4; ++q) {
        float4 m = mp[q], v = vp[q], e = ep[q];
        x[4*q+0] = e.x * __expf(0.5f * v.x) + m.x;
        x[4*q+1] = e.y * __expf(0.5f * v.y) + m.y;
        x[4*q+2] = e.z * __expf(0.5f * v.z) + m.z;
        x[4*q+3] = e.w * __expf(0.5f * v.w) + m.w;
    }
    float m1 = 0.f, qq = 0.f;
    #pragma unroll 4
    for (int p = 0; p < 16; ++p) {
        float sp = 0.f;
        #pragma unroll
        for (int q2 = 0; q2 < 16; ++q2) sp += Scs[p * 16 + q2] * x[q2];
        qq += x[p] * sp;
        m1 += Scs[256 + p] * x[p];
    }
    const float inv = 1.f / 256.f;
    m1 *= inv; qq *= inv;
    const float rs = rsqf(qq - m1 * m1 + LN_EPS);
    repS[gid] = make_float2(m1, rs);
    f16x8 H0, H1, L0, L1;
    #pragma unroll
    for (int f = 0; f < 8; ++f) {
        _Float16 h0_ = (_Float16)x[f];
        H0[f] = h0_; L0[f] = (_Float16)((x[f] - (float)h0_) * LSC);
        _Float16 h1_ = (_Float16)x[8 + f];
        H1[f] = h1_; L1[f] = (_Float16)((x[8 + f] - (float)h1_) * LSC);
    }
    f16x8* dst = repXf + (size_t)gid * 4;
    dst[0] = H0; dst[1] = H1; dst[2] = L0; dst[3] = L1;
}

// -------- W_out -> fp16, pre-transposed into MFMA-frag-contiguous layout:
// Wt[kstep(300)][nt(10)][lane(64)][8], lane l=(m,lgrp): W[nt*16+m][kstep*32+lgrp*8+q] --------
__global__ __launch_bounds__(256)
void wconv_kernel(const float* __restrict__ W, _Float16* __restrict__ Wt)
{
    const int gid = blockIdx.x * 256 + threadIdx.x;      // 300*10*64 = 192000
    const int ks = gid / 640;
    const int rem = gid - ks * 640;
    const int nt = rem >> 6;
    const int l = rem & 63;
    const int row = nt * 16 + (l & 15);
    const int k = ks * 32 + (l >> 4) * 8;
    f16x8 v;
    #pragma unroll
    for (int q = 0; q < 8; ++q) v[q] = (_Float16)0.f;
    if (row < 150) {
        const float4* p = (const float4*)(W + (size_t)row * KK + k);
        float4 a = p[0], b = p[1];
        v[0] = (_Float16)a.x; v[1] = (_Float16)a.y; v[2] = (_Float16)a.z; v[3] = (_Float16)a.w;
        v[4] = (_Float16)b.x; v[5] = (_Float16)b.y; v[6] = (_Float16)b.z; v[7] = (_Float16)b.w;
    }
    *(f16x8*)(Wt + (size_t)gid * 8) = v;
}

// -------- MFMA LSTM: BB=4, 4-way mirrored A-rows ((m&3)); every thread's C element
// r=g is its own batch row -> scalar phase fully dedup'd, no cross-lane exchange.
// grid 512 = 2 blocks/CU for latency hiding. Named-scalar ternaries only. --------
__global__ __launch_bounds__(256, 1)
void lstm_kernel(const float* __restrict__ h0, const float* __restrict__ c0,
                 const float* __restrict__ W_ih, const float* __restrict__ W_hh,
                 const float* __restrict__ g_ih, const float* __restrict__ bln_ih,
                 const float* __restrict__ g_hh, const float* __restrict__ bln_hh,
                 const float* __restrict__ g_c, const float* __restrict__ bln_c,
                 const f16x8* __restrict__ repXf, const float2* __restrict__ repS,
                 _Float16* __restrict__ hs_out)
{
    const int tid = threadIdx.x;
    const int m = tid & 15;
    const int g = (tid >> 4) & 3;
    const int w = tid >> 6;
    const int row0 = blockIdx.x * BB;
    const int j = w * 16 + m;
    const bool gOdd = (g & 1) != 0;
    const bool gHi  = (g & 2) != 0;

    __shared__ _Float16 hH[BB * RS];
    __shared__ _Float16 hL[BB * RS];
    __shared__ float2 st1[BB][4];   // [row][w] : (sum, sumsq) of hh gates
    __shared__ float2 st2[BB][4];   // [row][w] : (sum, sumsq) of c

    // ---- static weight fragments (all 4 tn: MFMA is wave-collective) ----
    f16x8 WHf[4][2], WLf[4][2], Bi1[4], Bi2[4];
    float gihc[4], ghhc[4], bsc[4];
    const bool g01 = (g < 2);
    #pragma unroll
    for (int tn = 0; tn < 4; ++tn) {
        const int n = tn * 64 + j;
        #pragma unroll
        for (int c = 0; c < 2; ++c) {
            const float* wp = W_hh + n * 64 + c * 32 + g * 8;
            #pragma unroll
            for (int q = 0; q < 8; ++q) {
                float v = wp[q];
                _Float16 h_ = (_Float16)v;
                WHf[tn][c][q] = h_;
                WLf[tn][c][q] = (_Float16)((v - (float)h_) * LSC);
            }
        }
        const float* ip = W_ih + n * 16 + (g & 1) * 8;
        #pragma unroll
        for (int q = 0; q < 8; ++q) {
            float v = ip[q];
            _Float16 h_ = (_Float16)v;
            _Float16 l_ = (_Float16)((v - (float)h_) * LSC);
            Bi1[tn][q] = g01 ? h_ : (_Float16)0.f;   // pass1: [WH | 0]
            Bi2[tn][q] = g01 ? l_ : h_;              // pass2: [WL'| WH]
        }
        gihc[tn] = g_ih[n];
        ghhc[tn] = g_hh[n];
        bsc[tn] = bln_ih[n] + bln_hh[n];
    }
    const float gcc = g_c[j], bcc = bln_c[j];

    // ---- state init: c for own row (=g); h limbs in LDS (4 rows) ----
    float c_reg = c0[(size_t)(row0 + g) * HH + j];
    {
        const int rr = tid >> 6, jj = tid & 63;      // 4 rows x 64 j
        float hv = h0[(size_t)(row0 + rr) * HH + jj];
        _Float16 Hh = (_Float16)hv;
        hH[rr * RS + jj] = Hh;
        hL[rr * RS + jj] = (_Float16)((hv - (float)Hh) * LSC);
    }

    // x / stats prefetch (t=0); 4-way MIRRORED row (m&3)
    const size_t rowx = (size_t)row0 + (m & 3);
    f16x8 AX = repXf[rowx * 4 + g];
    float2 mrs = repS[row0 + g];
    __syncthreads();

    const float INV256 = 1.f / 256.f, INV64 = 1.f / 64.f;

    for (int t = 0; t < LCH; ++t) {
        // ---- A-frags (mirrored: lanes m, m+4, m+8, m+12 broadcast same row) ----
        const f16x8 AH0 = *(const f16x8*)&hH[(m & 3) * RS + g * 8];
        const f16x8 AH1 = *(const f16x8*)&hH[(m & 3) * RS + 32 + g * 8];
        const f16x8 AL0 = *(const f16x8*)&hL[(m & 3) * RS + g * 8];
        const f16x8 AL1 = *(const f16x8*)&hL[(m & 3) * RS + 32 + g * 8];

        f32x4 a1h[4], a2h[4], a1i[4], a2i[4];
        #pragma unroll
        for (int tn = 0; tn < 4; ++tn) {
            a1h[tn] = (f32x4)0.f; a2h[tn] = (f32x4)0.f;
            a1i[tn] = (f32x4)0.f; a2i[tn] = (f32x4)0.f;
        }
        #pragma unroll
        for (int tn = 0; tn < 4; ++tn) {
            a1h[tn] = __builtin_amdgcn_mfma_f32_16x16x32_f16(AH0, WHf[tn][0], a1h[tn], 0, 0, 0);
            a1h[tn] = __builtin_amdgcn_mfma_f32_16x16x32_f16(AH1, WHf[tn][1], a1h[tn], 0, 0, 0);
        }
        #pragma unroll
        for (int tn = 0; tn < 4; ++tn) {
            a2h[tn] = __builtin_amdgcn_mfma_f32_16x16x32_f16(AH0, WLf[tn][0], a2h[tn], 0, 0, 0);
            a2h[tn] = __builtin_amdgcn_mfma_f32_16x16x32_f16(AH1, WLf[tn][1], a2h[tn], 0, 0, 0);
            a2h[tn] = __builtin_amdgcn_mfma_f32_16x16x32_f16(AL0, WHf[tn][0], a2h[tn], 0, 0, 0);
            a2h[tn] = __builtin_amdgcn_mfma_f32_16x16x32_f16(AL1, WHf[tn][1], a2h[tn], 0, 0, 0);
        }
        #pragma unroll
        for (int tn = 0; tn < 4; ++tn) {
            a1i[tn] = __builtin_amdgcn_mfma_f32_16x16x32_f16(AX, Bi1[tn], a1i[tn], 0, 0, 0);
            a2i[tn] = __builtin_amdgcn_mfma_f32_16x16x32_f16(AX, Bi2[tn], a2i[tn], 0, 0, 0);
        }

        // ---- prefetch next step ----
        const int tp = (t + 1 < LCH) ? t + 1 : LCH - 1;
        const f16x8 AXn = repXf[((size_t)tp * 2048 + rowx) * 4 + g];
        const float2 mrsn = repS[(size_t)tp * 2048 + row0 + g];

        // ---- select own row (element r=g) via named scalars; limb combine ----
        float ohh[4], oih[4];
        #pragma unroll
        for (int tn = 0; tn < 4; ++tn) {
            const float p0 = a1h[tn][0], p1 = a1h[tn][1], p2 = a1h[tn][2], p3 = a1h[tn][3];
            const float q0 = a2h[tn][0], q1 = a2h[tn][1], q2 = a2h[tn][2], q3 = a2h[tn][3];
            const float ph = gHi ? (gOdd ? p3 : p2) : (gOdd ? p1 : p0);
            const float qh = gHi ? (gOdd ? q3 : q2) : (gOdd ? q1 : q0);
            ohh[tn] = fmaf(qh, ISC, ph);
            const float r0 = a1i[tn][0], r1 = a1i[tn][1], r2 = a1i[tn][2], r3 = a1i[tn][3];
            const float s0 = a2i[tn][0], s1 = a2i[tn][1], s2 = a2i[tn][2], s3 = a2i[tn][3];
            const float pi = gHi ? (gOdd ? r3 : r2) : (gOdd ? r1 : r0);
            const float qi = gHi ? (gOdd ? s3 : s2) : (gOdd ? s1 : s0);
            oih[tn] = fmaf(qi, ISC, pi);
        }

        // ---- LN-256 hh stats for own row ----
        {
            float s = red16((ohh[0] + ohh[1]) + (ohh[2] + ohh[3]));
            float qv = red16(ohh[0]*ohh[0] + ohh[1]*ohh[1] + ohh[2]*ohh[2] + ohh[3]*ohh[3]);
            if (m == 0) st1[g][w] = make_float2(s, qv);
        }
        __syncthreads();   // B1

        float2 u0 = st1[g][0], u1 = st1[g][1], u2 = st1[g][2], u3 = st1[g][3];
        const float S1 = (u0.x + u1.x) + (u2.x + u3.x);
        const float Q1 = (u0.y + u1.y) + (u2.y + u3.y);
        const float mh = S1 * INV256;
        const float rsh = rsqf(Q1 * INV256 - mh * mh + LN_EPS);
        const float mi = mrs.x, rsi = mrs.y;

        // ---- all 4 gates for own row (4 exp-chains) ----
        float act0, act1, act2, act3;
        {
            float ga = (ohh[0] - mh) * rsh * ghhc[0] + (oih[0] - mi) * rsi * gihc[0] + bsc[0];
            act0 = rcpf(1.f + __expf(-ga));
            float gb = (ohh[1] - mh) * rsh * ghhc[1] + (oih[1] - mi) * rsi * gihc[1] + bsc[1];
            act1 = rcpf(1.f + __expf(-gb));
            float gc2 = (ohh[2] - mh) * rsh * ghhc[2] + (oih[2] - mi) * rsi * gihc[2] + bsc[2];
            act2 = 2.f * rcpf(1.f + __expf(-2.f * gc2)) - 1.f;
            float gd = (ohh[3] - mh) * rsh * ghhc[3] + (oih[3] - mi) * rsi * gihc[3] + bsc[3];
            act3 = rcpf(1.f + __expf(-gd));
        }

        // ---- c update + LN-64 stats ----
        c_reg = fmaf(act1, c_reg, act0 * act2);
        {
            float sc = red16(c_reg);
            float qc = red16(c_reg * c_reg);
            if (m == 0) st2[g][w] = make_float2(sc, qc);
        }
        __syncthreads();   // B2

        {
            float2 v0 = st2[g][0], v1 = st2[g][1], v2 = st2[g][2], v3 = st2[g][3];
            const float Sc = (v0.x + v1.x) + (v2.x + v3.x);
            const float Qc = (v0.y + v1.y) + (v2.y + v3.y);
            const float mc = Sc * INV64;
            const float rsc = rsqf(Qc * INV64 - mc * mc + LN_EPS);
            const float lnc = (c_reg - mc) * rsc * gcc + bcc;
            const float th = 2.f * rcpf(1.f + __expf(-2.f * lnc)) - 1.f;
            const float h = act3 * th;
            _Float16 Hh = (_Float16)h;
            hH[g * RS + j] = Hh;
            hL[g * RS + j] = (_Float16)((h - (float)Hh) * LSC);
            hs_out[(size_t)(row0 + g) * KK + t * HH + j] = (_Float16)h;
        }
        __syncthreads();   // B3

        AX = AXn; mrs = mrsn;
    }
}

// -------- MFMA output GEMM: fp16 single-limb, 128 rows/block, frag-contiguous B.
// grid (16, 16) = 256 blocks; uneven K split: segs 0-11 get 19 k32-steps, 12-15 get 18. --------
__global__ __launch_bounds__(256)
void gemm_kernel(const _Float16* __restrict__ hs,
                 const _Float16* __restrict__ Wt,
                 float* __restrict__ partial)
{
    const int mb = blockIdx.x;       // 0..15 (128 rows)
    const int seg = blockIdx.y;      // 0..15
    const int tid = threadIdx.x;
    const int l = tid & 63;
    const int w = tid >> 6;
    const int m = l & 15;
    const int lgrp = l >> 4;

    f32x4 acc[2][10];
    #pragma unroll
    for (int iA = 0; iA < 2; ++iA)
        #pragma unroll
        for (int nt = 0; nt < 10; ++nt) acc[iA][nt] = (f32x4)0.f;

    const int s0 = seg * 18 + (seg < 12 ? seg : 12);
    const int nst = 18 + (seg < 12 ? 1 : 0);

    const _Float16* ap0 = hs + (size_t)(mb * 128 + w * 16 + m) * KK + lgrp * 8;
    const _Float16* ap1 = ap0 + (size_t)64 * KK;

    for (int s = s0; s < s0 + nst; ++s) {
        const f16x8 A0 = *(const f16x8*)(ap0 + s * 32);
        const f16x8 A1 = *(const f16x8*)(ap1 + s * 32);
        const _Float16* bp = Wt + ((size_t)s * 640 + l) * 8;
        #pragma unroll
        for (int nt = 0; nt < 10; ++nt) {
            const f16x8 Bv = *(const f16x8*)(bp + nt * 512);
            acc[0][nt] = __builtin_amdgcn_mfma_f32_16x16x32_f16(A0, Bv, acc[0][nt], 0, 0, 0);
            acc[1][nt] = __builtin_amdgcn_mfma_f32_16x16x32_f16(A1, Bv, acc[1][nt], 0, 0, 0);
        }
    }
    #pragma unroll
    for (int iA = 0; iA < 2; ++iA) {
        float* po = partial + ((size_t)seg * B_SZ + mb * 128 + iA * 64 + w * 16 + lgrp * 4) * NPAD + m;
        #pragma unroll
        for (int nt = 0; nt < 10; ++nt)
            #pragma unroll
            for (int r = 0; r < 4; ++r)
                po[(size_t)r * NPAD + nt * 16] = acc[iA][nt][r];
    }
}

__global__ __launch_bounds__(256)
void reduce_kernel(const float* __restrict__ partial, const float* __restrict__ b_out,
                   float* __restrict__ out)
{
    const int i = blockIdx.x * 256 + threadIdx.x;   // row*150 + c
    const int row = i / 150;
    const int c = i - row * 150;
    float s = 0.f;
    #pragma unroll
    for (int g = 0; g < NSEG; ++g)
        s += partial[((size_t)g * B_SZ + row) * NPAD + c];
    out[i] = s + b_out[c];
}

extern "C" void kernel_launch(void* const* d_in, const int* in_sizes, int n_in,
                              void* d_out, int out_size, void* d_ws, size_t ws_size,
                              hipStream_t stream)
{
    const int*   idx        = (const int*)  d_in[0];
    const float* eps        = (const float*)d_in[1];
    const float* h0         = (const float*)d_in[2];
    const float* c0         = (const float*)d_in[3];
    const float* mean_table = (const float*)d_in[4];
    const float* var_table  = (const float*)d_in[5];
    const float* W_ih       = (const float*)d_in[6];
    const float* W_hh       = (const float*)d_in[7];
    const float* g_ih       = (const float*)d_in[8];
    const float* bln_ih     = (const float*)d_in[9];
    const float* g_hh       = (const float*)d_in[10];
    const float* bln_hh     = (const float*)d_in[11];
    const float* g_c        = (const float*)d_in[12];
    const float* bln_c      = (const float*)d_in[13];
    const float* W_out      = (const float*)d_in[14];
    const float* b_out      = (const float*)d_in[15];
    float* out = (float*)d_out;

    // ws layout (temporal aliasing):
    //  phase 1 (wstat/prep/lstm):  [0,19.66M)=repXf  [19.66,22.12M)=repS
    //  phase 2 (wconv/gemm/red):   [0,3.07M)=Wt fp16 [3.07,24.04M)=partial[16][2048][160]
    //  always: [24.05M, 63.37M)=hs fp16 ; [63.37M,+1088B)=Scs
    char* wsb = (char*)d_ws;
    const size_t repXf_b = (size_t)LCH * B_SZ * 64;        // 19,660,800
    const size_t repS_b  = (size_t)LCH * B_SZ * 8;         //  2,457,600
    const size_t wt_b    = (size_t)300 * 640 * 8 * 2;      //  3,072,000
    const size_t part_b  = (size_t)NSEG * B_SZ * NPAD * 4; // 20,971,520
    const size_t hs_off  = wt_b + part_b;                  // 24,043,520 > repXf+repS
    const size_t hs_b    = (size_t)B_SZ * KK * 2;          // 39,321,600

    f16x8* repXf = (f16x8*)wsb;
    float2* repS = (float2*)(wsb + repXf_b);
    _Float16* Wt = (_Float16*)wsb;
    float* partial = (float*)(wsb + wt_b);
    _Float16* hs = (_Float16*)(wsb + hs_off);
    float* Scs = (float*)(wsb + hs_off + hs_b);

    const size_t need = hs_off + hs_b + 272 * 4;
    if (ws_size < need) return;

    wstat_kernel<<<1, 256, 0, stream>>>(W_ih, Scs);
    prep_kernel<<<(B_SZ * LCH) / 256, 256, 0, stream>>>(idx, eps, mean_table, var_table,
                                                        Scs, repXf, repS);
    lstm_kernel<<<B_SZ / BB, 256, 0, stream>>>(h0, c0, W_ih, W_hh, g_ih, bln_ih,
                                               g_hh, bln_hh, g_c, bln_c,
                                               repXf, repS, hs);
    wconv_kernel<<<750, 256, 0, stream>>>(W_out, Wt);
    gemm_kernel<<<dim3(16, NSEG), 256, 0, stream>>>(hs, Wt, partial);
    reduce_kernel<<<(B_SZ * LCH) / 256, 256, 0, stream>>>(partial, b_out, out);
}

// Round 10
// 252.808 us; speedup vs baseline: 4.9382x; 1.0567x over previous
//
#include <hip/hip_runtime.h>
#include <hip/hip_bf16.h>

#define LN_EPS 1e-5f
#define B_SZ 2048
#define LCH 150
#define HH 64
#define KK 9600
#define NSEG 16
#define NPAD 160
#define BB 4
#define RS 72
#define LSC 4096.0f
#define ISC (1.0f/4096.0f)

typedef __attribute__((ext_vector_type(8))) _Float16 f16x8;
typedef __attribute__((ext_vector_type(4))) float f32x4;

__device__ __forceinline__ float rcpf(float x) { return __builtin_amdgcn_rcpf(x); }
__device__ __forceinline__ float rsqf(float x) { return __builtin_amdgcn_rsqf(x); }

template<int CTRL>
__device__ __forceinline__ float dppadd16(float x) {
    int y = __builtin_amdgcn_update_dpp(0, __float_as_int(x), CTRL, 0xf, 0xf, true);
    return x + __int_as_float(y);
}
// sum within each 16-lane group (all lanes end with the sum)
__device__ __forceinline__ float red16(float x) {
    x = dppadd16<0xB1>(x);   // quad_perm 1,0,3,2
    x = dppadd16<0x4E>(x);   // quad_perm 2,3,0,1
    x = dppadd16<0x141>(x);  // row_half_mirror
    x = dppadd16<0x140>(x);  // row_mirror
    return x;
}

// -------- stats of W_ih: S = sum_n w_n w_n^T (16x16), cs = sum_n w_n --------
__global__ __launch_bounds__(256)
void wstat_kernel(const float* __restrict__ W_ih, float* __restrict__ Scs)
{
    const int tid = threadIdx.x;
    const int p = tid >> 4, q = tid & 15;
    float s = 0.f;
    for (int n = 0; n < 256; ++n)
        s += W_ih[n * 16 + p] * W_ih[n * 16 + q];
    Scs[p * 16 + q] = s;
    if (tid < 16) {
        float c = 0.f;
        for (int n = 0; n < 256; ++n) c += W_ih[n * 16 + tid];
        Scs[256 + tid] = c;
    }
}

// -------- prep: rep = eps*exp(0.5*logvar)+mu; fp16 limb A-frags + ih LN stats --------
__global__ __launch_bounds__(256)
void prep_kernel(const int* __restrict__ idx, const float* __restrict__ eps,
                 const float* __restrict__ mean_table, const float* __restrict__ var_table,
                 const float* __restrict__ Scs,
                 f16x8* __restrict__ repXf, float2* __restrict__ repS)
{
    const int gid = blockIdx.x * 256 + threadIdx.x;      // t*2048 + b
    const int t = gid >> 11, b = gid & 2047;
    const int id = idx[b * LCH + t];
    const float4* mp = (const float4*)(mean_table + (size_t)id * 16);
    const float4* vp = (const float4*)(var_table + (size_t)id * 16);
    const float4* ep = (const float4*)(eps + ((size_t)b * LCH + t) * 16);
    float x[16];
    #pragma unroll
    for (int q = 0; q < 4; ++q) {
        float4 m = mp[q], v = vp[q], e = ep[q];
        x[4*q+0] = e.x * __expf(0.5f * v.x) + m.x;
        x[4*q+1] = e.y * __expf(0.5f * v.y) + m.y;
        x[4*q+2] = e.z * __expf(0.5f * v.z) + m.z;
        x[4*q+3] = e.w * __expf(0.5f * v.w) + m.w;
    }
    float m1 = 0.f, qq = 0.f;
    #pragma unroll 4
    for (int p = 0; p < 16; ++p) {
        float sp = 0.f;
        #pragma unroll
        for (int q2 = 0; q2 < 16; ++q2) sp += Scs[p * 16 + q2] * x[q2];
        qq += x[p] * sp;
        m1 += Scs[256 + p] * x[p];
    }
    const float inv = 1.f / 256.f;
    m1 *= inv; qq *= inv;
    const float rs = rsqf(qq - m1 * m1 + LN_EPS);
    repS[gid] = make_float2(m1, rs);
    f16x8 H0, H1, L0, L1;
    #pragma unroll
    for (int f = 0; f < 8; ++f) {
        _Float16 h0_ = (_Float16)x[f];
        H0[f] = h0_; L0[f] = (_Float16)((x[f] - (float)h0_) * LSC);
        _Float16 h1_ = (_Float16)x[8 + f];
        H1[f] = h1_; L1[f] = (_Float16)((x[8 + f] - (float)h1_) * LSC);
    }
    f16x8* dst = repXf + (size_t)gid * 4;
    dst[0] = H0; dst[1] = H1; dst[2] = L0; dst[3] = L1;
}

// -------- W_out -> fp16, pre-transposed into MFMA-frag-contiguous layout:
// Wt[kstep(300)][nt(10)][lane(64)][8], lane l=(m,lgrp): W[nt*16+m][kstep*32+lgrp*8+q] --------
__global__ __launch_bounds__(256)
void wconv_kernel(const float* __restrict__ W, _Float16* __restrict__ Wt)
{
    const int gid = blockIdx.x * 256 + threadIdx.x;      // 300*10*64 = 192000
    const int ks = gid / 640;
    const int rem = gid - ks * 640;
    const int nt = rem >> 6;
    const int l = rem & 63;
    const int row = nt * 16 + (l & 15);
    const int k = ks * 32 + (l >> 4) * 8;
    f16x8 v;
    #pragma unroll
    for (int q = 0; q < 8; ++q) v[q] = (_Float16)0.f;
    if (row < 150) {
        const float4* p = (const float4*)(W + (size_t)row * KK + k);
        float4 a = p[0], b = p[1];
        v[0] = (_Float16)a.x; v[1] = (_Float16)a.y; v[2] = (_Float16)a.z; v[3] = (_Float16)a.w;
        v[4] = (_Float16)b.x; v[5] = (_Float16)b.y; v[6] = (_Float16)b.z; v[7] = (_Float16)b.w;
    }
    *(f16x8*)(Wt + (size_t)gid * 8) = v;
}

// -------- MFMA LSTM: BB=4, QUAD-mirrored A-rows (row = m>>2) so C row q = batch
// row q>>2 -> ALL 4 acc elements of the thread at lane-group g hold row g: element 0
// is used directly, zero cndmask selection. Scalar phase fully dedup'd. --------
__global__ __launch_bounds__(256, 1)
void lstm_kernel(const float* __restrict__ h0, const float* __restrict__ c0,
                 const float* __restrict__ W_ih, const float* __restrict__ W_hh,
                 const float* __restrict__ g_ih, const float* __restrict__ bln_ih,
                 const float* __restrict__ g_hh, const float* __restrict__ bln_hh,
                 const float* __restrict__ g_c, const float* __restrict__ bln_c,
                 const f16x8* __restrict__ repXf, const float2* __restrict__ repS,
                 _Float16* __restrict__ hs_out)
{
    const int tid = threadIdx.x;
    const int m = tid & 15;
    const int g = (tid >> 4) & 3;
    const int w = tid >> 6;
    const int row0 = blockIdx.x * BB;
    const int j = w * 16 + m;

    __shared__ _Float16 hH[BB * RS];
    __shared__ _Float16 hL[BB * RS];
    __shared__ float2 st1[BB][4];   // [row][w] : (sum, sumsq) of hh gates
    __shared__ float2 st2[BB][4];   // [row][w] : (sum, sumsq) of c

    // ---- static weight fragments (all 4 tn: MFMA is wave-collective) ----
    f16x8 WHf[4][2], WLf[4][2], Bi1[4], Bi2[4];
    float gihc[4], ghhc[4], bsc[4];
    const bool g01 = (g < 2);
    #pragma unroll
    for (int tn = 0; tn < 4; ++tn) {
        const int n = tn * 64 + j;
        #pragma unroll
        for (int c = 0; c < 2; ++c) {
            const float* wp = W_hh + n * 64 + c * 32 + g * 8;
            #pragma unroll
            for (int q = 0; q < 8; ++q) {
                float v = wp[q];
                _Float16 h_ = (_Float16)v;
                WHf[tn][c][q] = h_;
                WLf[tn][c][q] = (_Float16)((v - (float)h_) * LSC);
            }
        }
        const float* ip = W_ih + n * 16 + (g & 1) * 8;
        #pragma unroll
        for (int q = 0; q < 8; ++q) {
            float v = ip[q];
            _Float16 h_ = (_Float16)v;
            _Float16 l_ = (_Float16)((v - (float)h_) * LSC);
            Bi1[tn][q] = g01 ? h_ : (_Float16)0.f;   // pass1: [WH | 0]
            Bi2[tn][q] = g01 ? l_ : h_;              // pass2: [WL'| WH]
        }
        gihc[tn] = g_ih[n];
        ghhc[tn] = g_hh[n];
        bsc[tn] = bln_ih[n] + bln_hh[n];
    }
    const float gcc = g_c[j], bcc = bln_c[j];

    // ---- state init: c for own row (=g); h limbs in LDS (4 rows) ----
    float c_reg = c0[(size_t)(row0 + g) * HH + j];
    {
        const int rr = tid >> 6, jj = tid & 63;      // 4 rows x 64 j
        float hv = h0[(size_t)(row0 + rr) * HH + jj];
        _Float16 Hh = (_Float16)hv;
        hH[rr * RS + jj] = Hh;
        hL[rr * RS + jj] = (_Float16)((hv - (float)Hh) * LSC);
    }

    // x / stats prefetch (t=0); QUAD-mirrored row (m>>2)
    const size_t rowx = (size_t)row0 + (m >> 2);
    f16x8 AX = repXf[rowx * 4 + g];
    float2 mrs = repS[row0 + g];
    __syncthreads();

    const float INV256 = 1.f / 256.f, INV64 = 1.f / 64.f;

    for (int t = 0; t < LCH; ++t) {
        // ---- A-frags (quad-mirror: lanes 4u..4u+3 broadcast batch row u) ----
        const f16x8 AH0 = *(const f16x8*)&hH[(m >> 2) * RS + g * 8];
        const f16x8 AH1 = *(const f16x8*)&hH[(m >> 2) * RS + 32 + g * 8];
        const f16x8 AL0 = *(const f16x8*)&hL[(m >> 2) * RS + g * 8];
        const f16x8 AL1 = *(const f16x8*)&hL[(m >> 2) * RS + 32 + g * 8];

        f32x4 a1h[4], a2h[4], a1i[4], a2i[4];
        #pragma unroll
        for (int tn = 0; tn < 4; ++tn) {
            a1h[tn] = (f32x4)0.f; a2h[tn] = (f32x4)0.f;
            a1i[tn] = (f32x4)0.f; a2i[tn] = (f32x4)0.f;
        }
        #pragma unroll
        for (int tn = 0; tn < 4; ++tn) {
            a1h[tn] = __builtin_amdgcn_mfma_f32_16x16x32_f16(AH0, WHf[tn][0], a1h[tn], 0, 0, 0);
            a1h[tn] = __builtin_amdgcn_mfma_f32_16x16x32_f16(AH1, WHf[tn][1], a1h[tn], 0, 0, 0);
        }
        #pragma unroll
        for (int tn = 0; tn < 4; ++tn) {
            a2h[tn] = __builtin_amdgcn_mfma_f32_16x16x32_f16(AH0, WLf[tn][0], a2h[tn], 0, 0, 0);
            a2h[tn] = __builtin_amdgcn_mfma_f32_16x16x32_f16(AH1, WLf[tn][1], a2h[tn], 0, 0, 0);
            a2h[tn] = __builtin_amdgcn_mfma_f32_16x16x32_f16(AL0, WHf[tn][0], a2h[tn], 0, 0, 0);
            a2h[tn] = __builtin_amdgcn_mfma_f32_16x16x32_f16(AL1, WHf[tn][1], a2h[tn], 0, 0, 0);
        }
        #pragma unroll
        for (int tn = 0; tn < 4; ++tn) {
            a1i[tn] = __builtin_amdgcn_mfma_f32_16x16x32_f16(AX, Bi1[tn], a1i[tn], 0, 0, 0);
            a2i[tn] = __builtin_amdgcn_mfma_f32_16x16x32_f16(AX, Bi2[tn], a2i[tn], 0, 0, 0);
        }

        // ---- prefetch next step ----
        const int tp = (t + 1 < LCH) ? t + 1 : LCH - 1;
        const f16x8 AXn = repXf[((size_t)tp * 2048 + rowx) * 4 + g];
        const float2 mrsn = repS[(size_t)tp * 2048 + row0 + g];

        // ---- own row = element 0 (all elements identical); limb combine ----
        float ohh[4], oih[4];
        #pragma unroll
        for (int tn = 0; tn < 4; ++tn) {
            ohh[tn] = fmaf(a2h[tn][0], ISC, a1h[tn][0]);
            oih[tn] = fmaf(a2i[tn][0], ISC, a1i[tn][0]);
        }

        // ---- LN-256 hh stats for own row ----
        {
            float s = red16((ohh[0] + ohh[1]) + (ohh[2] + ohh[3]));
            float qv = red16(ohh[0]*ohh[0] + ohh[1]*ohh[1] + ohh[2]*ohh[2] + ohh[3]*ohh[3]);
            if (m == 0) st1[g][w] = make_float2(s, qv);
        }
        __syncthreads();   // B1

        float2 u0 = st1[g][0], u1 = st1[g][1], u2 = st1[g][2], u3 = st1[g][3];
        const float S1 = (u0.x + u1.x) + (u2.x + u3.x);
        const float Q1 = (u0.y + u1.y) + (u2.y + u3.y);
        const float mh = S1 * INV256;
        const float rsh = rsqf(Q1 * INV256 - mh * mh + LN_EPS);
        const float mi = mrs.x, rsi = mrs.y;

        // ---- all 4 gates for own row (4 exp-chains) ----
        float act0, act1, act2, act3;
        {
            float ga = (ohh[0] - mh) * rsh * ghhc[0] + (oih[0] - mi) * rsi * gihc[0] + bsc[0];
            act0 = rcpf(1.f + __expf(-ga));
            float gb = (ohh[1] - mh) * rsh * ghhc[1] + (oih[1] - mi) * rsi * gihc[1] + bsc[1];
            act1 = rcpf(1.f + __expf(-gb));
            float gc2 = (ohh[2] - mh) * rsh * ghhc[2] + (oih[2] - mi) * rsi * gihc[2] + bsc[2];
            act2 = 2.f * rcpf(1.f + __expf(-2.f * gc2)) - 1.f;
            float gd = (ohh[3] - mh) * rsh * ghhc[3] + (oih[3] - mi) * rsi * gihc[3] + bsc[3];
            act3 = rcpf(1.f + __expf(-gd));
        }

        // ---- c update + LN-64 stats ----
        c_reg = fmaf(act1, c_reg, act0 * act2);
        {
            float sc = red16(c_reg);
            float qc = red16(c_reg * c_reg);
            if (m == 0) st2[g][w] = make_float2(sc, qc);
        }
        __syncthreads();   // B2

        {
            float2 v0 = st2[g][0], v1 = st2[g][1], v2 = st2[g][2], v3 = st2[g][3];
            const float Sc = (v0.x + v1.x) + (v2.x + v3.x);
            const float Qc = (v0.y + v1.y) + (v2.y + v3.y);
            const float mc = Sc * INV64;
            const float rsc = rsqf(Qc * INV64 - mc * mc + LN_EPS);
            const float lnc = (c_reg - mc) * rsc * gcc + bcc;
            const float th = 2.f * rcpf(1.f + __expf(-2.f * lnc)) - 1.f;
            const float h = act3 * th;
            _Float16 Hh = (_Float16)h;
            hH[g * RS + j] = Hh;
            hL[g * RS + j] = (_Float16)((h - (float)Hh) * LSC);
            hs_out[(size_t)(row0 + g) * KK + t * HH + j] = (_Float16)h;
        }
        __syncthreads();   // B3

        AX = AXn; mrs = mrsn;
    }
}

// -------- MFMA output GEMM: fp16 single-limb, 128 rows/block, frag-contiguous B.
// grid (16, 16) = 256 blocks; uneven K split: segs 0-11 get 19 k32-steps, 12-15 get 18. --------
__global__ __launch_bounds__(256)
void gemm_kernel(const _Float16* __restrict__ hs,
                 const _Float16* __restrict__ Wt,
                 float* __restrict__ partial)
{
    const int mb = blockIdx.x;       // 0..15 (128 rows)
    const int seg = blockIdx.y;      // 0..15
    const int tid = threadIdx.x;
    const int l = tid & 63;
    const int w = tid >> 6;
    const int m = l & 15;
    const int lgrp = l >> 4;

    f32x4 acc[2][10];
    #pragma unroll
    for (int iA = 0; iA < 2; ++iA)
        #pragma unroll
        for (int nt = 0; nt < 10; ++nt) acc[iA][nt] = (f32x4)0.f;

    const int s0 = seg * 18 + (seg < 12 ? seg : 12);
    const int nst = 18 + (seg < 12 ? 1 : 0);

    const _Float16* ap0 = hs + (size_t)(mb * 128 + w * 16 + m) * KK + lgrp * 8;
    const _Float16* ap1 = ap0 + (size_t)64 * KK;

    for (int s = s0; s < s0 + nst; ++s) {
        const f16x8 A0 = *(const f16x8*)(ap0 + s * 32);
        const f16x8 A1 = *(const f16x8*)(ap1 + s * 32);
        const _Float16* bp = Wt + ((size_t)s * 640 + l) * 8;
        #pragma unroll
        for (int nt = 0; nt < 10; ++nt) {
            const f16x8 Bv = *(const f16x8*)(bp + nt * 512);
            acc[0][nt] = __builtin_amdgcn_mfma_f32_16x16x32_f16(A0, Bv, acc[0][nt], 0, 0, 0);
            acc[1][nt] = __builtin_amdgcn_mfma_f32_16x16x32_f16(A1, Bv, acc[1][nt], 0, 0, 0);
        }
    }
    #pragma unroll
    for (int iA = 0; iA < 2; ++iA) {
        float* po = partial + ((size_t)seg * B_SZ + mb * 128 + iA * 64 + w * 16 + lgrp * 4) * NPAD + m;
        #pragma unroll
        for (int nt = 0; nt < 10; ++nt)
            #pragma unroll
            for (int r = 0; r < 4; ++r)
                po[(size_t)r * NPAD + nt * 16] = acc[iA][nt][r];
    }
}

__global__ __launch_bounds__(256)
void reduce_kernel(const float* __restrict__ partial, const float* __restrict__ b_out,
                   float* __restrict__ out)
{
    const int i = blockIdx.x * 256 + threadIdx.x;   // row*150 + c
    const int row = i / 150;
    const int c = i - row * 150;
    float s = 0.f;
    #pragma unroll
    for (int g = 0; g < NSEG; ++g)
        s += partial[((size_t)g * B_SZ + row) * NPAD + c];
    out[i] = s + b_out[c];
}

extern "C" void kernel_launch(void* const* d_in, const int* in_sizes, int n_in,
                              void* d_out, int out_size, void* d_ws, size_t ws_size,
                              hipStream_t stream)
{
    const int*   idx        = (const int*)  d_in[0];
    const float* eps        = (const float*)d_in[1];
    const float* h0         = (const float*)d_in[2];
    const float* c0         = (const float*)d_in[3];
    const float* mean_table = (const float*)d_in[4];
    const float* var_table  = (const float*)d_in[5];
    const float* W_ih       = (const float*)d_in[6];
    const float* W_hh       = (const float*)d_in[7];
    const float* g_ih       = (const float*)d_in[8];
    const float* bln_ih     = (const float*)d_in[9];
    const float* g_hh       = (const float*)d_in[10];
    const float* bln_hh     = (const float*)d_in[11];
    const float* g_c        = (const float*)d_in[12];
    const float* bln_c      = (const float*)d_in[13];
    const float* W_out      = (const float*)d_in[14];
    const float* b_out      = (const float*)d_in[15];
    float* out = (float*)d_out;

    // ws layout (temporal aliasing):
    //  phase 1 (wstat/prep/lstm):  [0,19.66M)=repXf  [19.66,22.12M)=repS
    //  phase 2 (wconv/gemm/red):   [0,3.07M)=Wt fp16 [3.07,24.04M)=partial[16][2048][160]
    //  always: [24.05M, 63.37M)=hs fp16 ; [63.37M,+1088B)=Scs
    char* wsb = (char*)d_ws;
    const size_t repXf_b = (size_t)LCH * B_SZ * 64;        // 19,660,800
    const size_t repS_b  = (size_t)LCH * B_SZ * 8;         //  2,457,600
    const size_t wt_b    = (size_t)300 * 640 * 8 * 2;      //  3,072,000
    const size_t part_b  = (size_t)NSEG * B_SZ * NPAD * 4; // 20,971,520
    const size_t hs_off  = wt_b + part_b;                  // 24,043,520 > repXf+repS
    const size_t hs_b    = (size_t)B_SZ * KK * 2;          // 39,321,600

    f16x8* repXf = (f16x8*)wsb;
    float2* repS = (float2*)(wsb + repXf_b);
    _Float16* Wt = (_Float16*)wsb;
    float* partial = (float*)(wsb + wt_b);
    _Float16* hs = (_Float16*)(wsb + hs_off);
    float* Scs = (float*)(wsb + hs_off + hs_b);

    const size_t need = hs_off + hs_b + 272 * 4;
    if (ws_size < need) return;

    wstat_kernel<<<1, 256, 0, stream>>>(W_ih, Scs);
    prep_kernel<<<(B_SZ * LCH) / 256, 256, 0, stream>>>(idx, eps, mean_table, var_table,
                                                        Scs, repXf, repS);
    lstm_kernel<<<B_SZ / BB, 256, 0, stream>>>(h0, c0, W_ih, W_hh, g_ih, bln_ih,
                                               g_hh, bln_hh, g_c, bln_c,
                                               repXf, repS, hs);
    wconv_kernel<<<750, 256, 0, stream>>>(W_out, Wt);
    gemm_kernel<<<dim3(16, NSEG), 256, 0, stream>>>(hs, Wt, partial);
    reduce_kernel<<<(B_SZ * LCH) / 256, 256, 0, stream>>>(partial, b_out, out);
}